// Round 6
// baseline (3362.183 us; speedup 1.0000x reference)
//
#include <hip/hip_runtime.h>

#define BB 32
#define TT 400
#define HH 512
#define NSTEP 100
#define VO 511
#define LSEQ 101
#define NBLK 256
#define NTHR 512
#define AOFF (BB*NSTEP*VO)
#define AXP 416   // per-b ax stride, 128B multiple (no cache line spans producers)
#define AG __HIP_MEMORY_SCOPE_AGENT

typedef float f4 __attribute__((ext_vector_type(4)));
typedef _Float16 hf8 __attribute__((ext_vector_type(8)));

struct P {
  const float* x; const int* y; const float* emb;
  const float* wih; const float* whh; const float* bih; const float* bhh;
  const float* cw; const float* cb; const float* aw; const float* ab;
  const float* fw; const float* fb;
  float* out; int* ctrl; float* fws; _Float16* xh; int deep;
};

__device__ __forceinline__ float wredsum(float v) {
#pragma unroll
  for (int d = 1; d < 64; d <<= 1) v += __shfl_xor(v, d, 64);
  return v;
}

__device__ __forceinline__ void dot4f(float& acc, f4 wv, f4 av) {
  acc = fmaf(wv.x, av.x, fmaf(wv.y, av.y, fmaf(wv.z, av.z, fmaf(wv.w, av.w, acc))));
}

// uncached (coherence-point) ops for cross-block small data / flags
__device__ __forceinline__ float gld(const float* q) {
  return __hip_atomic_load(q, __ATOMIC_RELAXED, AG);
}
__device__ __forceinline__ void gst(float* q, float v) {
  __hip_atomic_store(q, v, __ATOMIC_RELAXED, AG);
}
// rotating-buffer read: cached when write-once rotation (deep), else bypass
__device__ __forceinline__ float ldr(const float* q, int deep) {
  return deep ? *q : gld(q);
}

__global__ __launch_bounds__(NTHR, 2) void seq2seq_kernel(P p) {
  const int tid  = threadIdx.x;
  const int lane = tid & 63;
  const int wave = tid >> 6;
  const int blk  = blockIdx.x;
  const int sb    = blk >> 3;   // score group batch
  const int tch   = blk & 7;
  const int t0    = tch * 50;
  const int btile = blk >> 6;   // phase3 b-tile (covers b = btile*8..+8; sb is inside)
  const int hblk  = blk & 63;
  const int bbase = btile * 8;
  const int hg    = hblk * 8 + wave;
  const int h0s   = lane * 8;
  const int deep  = p.deep;
  const int D     = deep ? NSTEP : 4;

  __shared__ __align__(16) float smem[12288];   // 48 KB unioned arena
  float* axs  = smem;               // [68]      (score)
  float* accS = smem + 128;         // [8][512]  (score)
  float* mS   = smem + 128 + 4096;  // [8]
  float* lS   = mS + 8;             // [8]
  float* Avec = smem;               // [8][1024] (phase3)
  float* Bvec = smem + 8192;        // [8][512]  (phase3)
  __shared__ int combf;

  float* hxr_buf = p.fws;                              // [D][BB][HH]
  float* sxr_buf = hxr_buf + (size_t)D*BB*HH;          // [D][BB][HH]
  float* axr_buf = sxr_buf + (size_t)D*BB*HH;          // [D][BB][AXP]
  float* scg  = axr_buf + (size_t)D*BB*AXP;            // [BB][TT]   (uncached)
  float* pm   = scg + BB*TT;                           // [BB*8]
  float* pl   = pm + 256;
  float* pacc = pl + 256;                              // [BB][8][HH]

  int* arrv  = p.ctrl;            // ticket[b] at [b*16]
  int* fcomb = p.ctrl + 1024;     // combine flag[b] at [1024+b*16]
  int* c3    = p.ctrl + 2048;     // phase3 counter[btile] at [2048+bt*16]

  // ---- persistent per-lane conv/attn weights ----
  float cwr[120];
  float cbr[8], awr[8];
#pragma unroll
  for (int j = 0; j < 8; ++j) {
    int h = h0s + j;
    cbr[j] = p.cb[h];
    awr[j] = p.aw[h];
#pragma unroll
    for (int k = 0; k < 15; ++k) cwr[j*15+k] = p.cw[h*15 + k];
  }
  const float atb = p.ab[0];

  // ---- one-time fp16 x-copy (keeps per-XCD working set < 4MB L2) ----
  {
#pragma unroll
    for (int it = 0; it < 7; ++it) {
      const bool valid = (it < 6) || (wave < 2);
      if (valid) {
        const int t = t0 + wave + it*8;
        const float* xp = p.x + ((size_t)sb*TT + t)*HH + h0s;
        f4 x0 = ((const f4*)xp)[0], x1 = ((const f4*)xp)[1];
        hf8 xv;
        xv[0]=(_Float16)x0.x; xv[1]=(_Float16)x0.y; xv[2]=(_Float16)x0.z; xv[3]=(_Float16)x0.w;
        xv[4]=(_Float16)x1.x; xv[5]=(_Float16)x1.y; xv[6]=(_Float16)x1.z; xv[7]=(_Float16)x1.w;
        *(hf8*)(p.xh + ((size_t)sb*TT + t)*HH + h0s) = xv;
      }
    }
    __syncthreads();
  }

  auto spin_ge = [&](int* addr, unsigned target) {
    while (__hip_atomic_load((unsigned*)addr, __ATOMIC_RELAXED, AG) < target)
      __builtin_amdgcn_s_sleep(1);
  };

  // ---- phase3(s): FC(s) + GRU producing hx[s+1]; gated on combine flags ----
  auto phase3 = [&](int s) {
    const bool dofc  = (s >= 0);
    const bool dogru = (s < NSTEP - 1);
    if (s >= 0) {
      if (tid < 8) spin_ge(&fcomb[(bbase + tid)*16], (unsigned)(s+1));
      __syncthreads();
    }
    const int sc_ = (s < 0) ? 0 : s;
    const float* hx_s = hxr_buf + (size_t)(sc_ % D)*BB*HH;
    const float* sx_s = sxr_buf + (size_t)(sc_ % D)*BB*HH;
#pragma unroll 1
    for (int b8 = 0; b8 < 8; ++b8) {
      const int b = bbase + b8;
      const int c = tid;
      float hxv = 0.f, sxv = 0.f;
      if (dofc) {
        hxv = ldr(hx_s + (size_t)b*HH + c, deep);
        sxv = ldr(sx_s + (size_t)b*HH + c, deep);
        Bvec[b8*512 + c] = hxv + sxv;
      }
      if (dogru) {
        const int yb = p.y[b*LSEQ + (s+1)];
        Avec[b8*1024 + c]       = p.emb[(size_t)yb*HH + c] + sxv;
        Avec[b8*1024 + 512 + c] = hxv;
      }
    }
    __syncthreads();
    if (dofc && hg < VO) {
      // k-chunks: lane*4 and 256+lane*4 -> conflict-free b128 LDS reads
      const float* fr = p.fw + (size_t)hg*HH;
      f4 fw0 = *(const f4*)(fr + lane*4);
      f4 fw1 = *(const f4*)(fr + lane*4 + 256);
      float fbv = p.fb[hg];
#pragma unroll 1
      for (int b8 = 0; b8 < 8; ++b8) {
        f4 b0 = *(const f4*)(&Bvec[b8*512 + lane*4]);
        f4 b1 = *(const f4*)(&Bvec[b8*512 + lane*4 + 256]);
        float d = 0.f;
        dot4f(d, fw0, b0); dot4f(d, fw1, b1);
        d = wredsum(d);
        if (lane == 0)
          p.out[(size_t)(bbase+b8)*NSTEP*VO + (size_t)s*VO + hg] = d + fbv;
      }
    }
    if (dogru) {
      const int half = lane >> 5, l5 = lane & 31;
      // k-chunks per half: l5*4 + q*128 -> conflict-free b128 LDS reads
      const float* base1 = half ? p.whh : p.wih;
      const float* r1 = base1 + (size_t)hg*HH;
      const float* r2 = base1 + (size_t)(512+hg)*HH;
      const float* r3 = base1 + (size_t)(1024+hg)*HH;
      f4 wr_[4], wz_[4], wn_[4];
#pragma unroll
      for (int q = 0; q < 4; ++q) {
        const int off = l5*4 + q*128;
        wr_[q] = *(const f4*)(r1 + off);
        wz_[q] = *(const f4*)(r2 + off);
        wn_[q] = *(const f4*)(r3 + off);
      }
      const float br  = p.bih[hg] + p.bhh[hg];
      const float bz  = p.bih[512+hg] + p.bhh[512+hg];
      const float bin = p.bih[1024+hg];
      const float bhn = p.bhh[1024+hg];
      float* hx_n = hxr_buf + (size_t)((s+1) % D)*BB*HH;
#pragma unroll 1
      for (int b8 = 0; b8 < 8; ++b8) {
        f4 a0 = *(const f4*)(&Avec[b8*1024 + half*512 + l5*4]);
        f4 a1 = *(const f4*)(&Avec[b8*1024 + half*512 + l5*4 + 128]);
        f4 a2 = *(const f4*)(&Avec[b8*1024 + half*512 + l5*4 + 256]);
        f4 a3 = *(const f4*)(&Avec[b8*1024 + half*512 + l5*4 + 384]);
        float d1 = 0.f, d2 = 0.f, d3 = 0.f;
        dot4f(d1, wr_[0], a0); dot4f(d1, wr_[1], a1); dot4f(d1, wr_[2], a2); dot4f(d1, wr_[3], a3);
        dot4f(d2, wz_[0], a0); dot4f(d2, wz_[1], a1); dot4f(d2, wz_[2], a2); dot4f(d2, wz_[3], a3);
        dot4f(d3, wn_[0], a0); dot4f(d3, wn_[1], a1); dot4f(d3, wn_[2], a2); dot4f(d3, wn_[3], a3);
#pragma unroll
        for (int dd = 1; dd <= 32; dd <<= 1) { d1 += __shfl_xor(d1, dd, 64); d2 += __shfl_xor(d2, dd, 64); }
#pragma unroll
        for (int dd = 1; dd <= 16; dd <<= 1) d3 += __shfl_xor(d3, dd, 64);
        float d3o = __shfl_xor(d3, 32, 64);
        float i_n = half ? d3o : d3;
        float h_n = half ? d3  : d3o;
        float rg = 1.f / (1.f + __expf(-(d1 + br)));
        float zg = 1.f / (1.f + __expf(-(d2 + bz)));
        float na = (i_n + bin) + rg * (h_n + bhn);
        float e2 = __expf(2.f * na);
        float nn = 1.f - 2.f / (e2 + 1.f);
        float hold = Avec[b8*1024 + 512 + hg];
        float hnew = (1.f - zg) * nn + zg * hold;
        if (lane == 0) gst(&hx_n[(size_t)(bbase+b8)*HH + hg], hnew);
      }
    }
    __syncthreads();
    if (tid == 0 && s < NSTEP - 1) {
      __builtin_amdgcn_s_waitcnt(0);   // drain hx writes before counter
      __hip_atomic_fetch_add((unsigned*)&c3[btile*16], 1u, __ATOMIC_RELAXED, AG);
    }
  };

  // ---- score(s): gated on per-btile phase3 counter ----
  auto score = [&](int s) {
    if (tid == 0) spin_ge(&c3[btile*16], (unsigned)(64*(s+1)));
    __syncthreads();
    const float* hx_s = hxr_buf + (size_t)(s % D)*BB*HH;
    if (s > 0) {
      const float* ax_p = axr_buf + (size_t)((s-1) % D)*BB*AXP + (size_t)sb*AXP;
      if (tid < 68) {
        int tg = t0 - 8 + tid;
        axs[tid] = (tg >= 0 && tg < TT) ? ldr(ax_p + tg, deep) : 0.f;
      }
      __syncthreads();
    }
    const float* hxp = hx_s + (size_t)sb*HH + h0s;
    float hxr[8];
#pragma unroll
    for (int j = 0; j < 8; ++j) hxr[j] = ldr(hxp + j, deep);
    float m = -1e30f, l = 0.f;
    float acc[8];
#pragma unroll
    for (int j = 0; j < 8; ++j) acc[j] = 0.f;
#pragma unroll 1
    for (int t = t0 + wave; t < t0 + 50; t += 8) {
      hf8 xv = *(const hf8*)(p.xh + ((size_t)sb*TT + t)*HH + h0s);
      float xr[8];
#pragma unroll
      for (int j = 0; j < 8; ++j) xr[j] = (float)xv[j];
      float cc[8];
      if (s > 0) {
        const int li0 = (t - t0) + 1;
        float axv[15];
#pragma unroll
        for (int k = 0; k < 15; ++k) axv[k] = axs[li0 + k];
#pragma unroll
        for (int j = 0; j < 8; ++j) {
          float a = cbr[j];
#pragma unroll
          for (int k = 0; k < 15; ++k) a = fmaf(cwr[j*15+k], axv[k], a);
          cc[j] = a;
        }
      } else {
#pragma unroll
        for (int j = 0; j < 8; ++j) cc[j] = 0.f;
      }
      float part = 0.f;
#pragma unroll
      for (int j = 0; j < 8; ++j) {
        float vv = xr[j] + hxr[j] + cc[j];
        vv = fmaxf(vv, 0.f);
        part = fmaf(vv, awr[j], part);
      }
      part = wredsum(part);
      float st = part + atb;
      if (lane == 0) gst(&scg[sb*TT + t], st);
      float mn  = fmaxf(m, st);
      float scl = __expf(m - mn);
      float pe  = __expf(st - mn);
      l = l * scl + pe;
#pragma unroll
      for (int j = 0; j < 8; ++j) acc[j] = fmaf(acc[j], scl, pe * xr[j]);
      m = mn;
    }
    {
      f4 s0 = {acc[0],acc[1],acc[2],acc[3]}, s1_ = {acc[4],acc[5],acc[6],acc[7]};
      ((f4*)(&accS[wave*512 + h0s]))[0] = s0;
      ((f4*)(&accS[wave*512 + h0s]))[1] = s1_;
      if (lane == 0) { mS[wave] = m; lS[wave] = l; }
    }
    __syncthreads();
    float mb = mS[0];
#pragma unroll
    for (int w = 1; w < 8; ++w) mb = fmaxf(mb, mS[w]);
    float lb = 0.f, ew[8];
#pragma unroll
    for (int w = 0; w < 8; ++w) { ew[w] = __expf(mS[w] - mb); lb = fmaf(ew[w], lS[w], lb); }
    float ab_ = 0.f;
#pragma unroll
    for (int w = 0; w < 8; ++w) ab_ = fmaf(ew[w], accS[w*512 + tid], ab_);
    gst(&pacc[(size_t)(sb*8 + tch)*HH + tid], ab_);
    if (tid == 0) { gst(&pm[sb*8+tch], mb); gst(&pl[sb*8+tch], lb); }
    __syncthreads();
    if (tid == 0) {
      __builtin_amdgcn_s_waitcnt(0);   // drain partials before ticket
      unsigned old = __hip_atomic_fetch_add((unsigned*)&arrv[sb*16], 1u, __ATOMIC_RELAXED, AG);
      combf = (old == 7u) ? 1 : 0;
      if (old == 7u)
        __hip_atomic_store((unsigned*)&arrv[sb*16], 0u, __ATOMIC_RELAXED, AG);
    }
    __syncthreads();
    if (combf) {   // owner block: combine -> sx(s), ax(s), aligns
      float pmv[8], plv[8];
#pragma unroll
      for (int c = 0; c < 8; ++c) { pmv[c] = gld(&pm[sb*8+c]); plv[c] = gld(&pl[sb*8+c]); }
      float mm2 = pmv[0];
#pragma unroll
      for (int c = 1; c < 8; ++c) mm2 = fmaxf(mm2, pmv[c]);
      float ls = 0.f, ee[8];
#pragma unroll
      for (int c = 0; c < 8; ++c) { ee[c] = __expf(pmv[c] - mm2); ls = fmaf(ee[c], plv[c], ls); }
      float inv = 1.f / ls;
      float sv = 0.f;
#pragma unroll
      for (int c = 0; c < 8; ++c) sv = fmaf(ee[c], gld(&pacc[(size_t)(sb*8+c)*HH + tid]), sv);
      gst(sxr_buf + (size_t)(s % D)*BB*HH + (size_t)sb*HH + tid, sv * inv);
      float* ax_w = axr_buf + (size_t)(s % D)*BB*AXP + (size_t)sb*AXP;
      for (int t = tid; t < TT; t += NTHR) {
        float a = __expf(gld(&scg[sb*TT + t]) - mm2) * inv;
        gst(ax_w + t, a);
        p.out[AOFF + (size_t)sb*NSTEP*TT + (size_t)s*TT + t] = a;
      }
      __syncthreads();
      if (tid == 0) {
        __builtin_amdgcn_s_waitcnt(0); // drain sx/ax before flag
        __hip_atomic_store((unsigned*)&fcomb[sb*16], (unsigned)(s+1), __ATOMIC_RELAXED, AG);
      }
    }
  };

  // ---- main sequence: one flag-gate per phase, no global barrier ----
  phase3(-1);   // GRU step 0 (hx=0, sx=0) -> hx_rot[0], c3 += 1
  for (int s = 0; s < NSTEP; ++s) {
    score(s);
    phase3(s);
  }
}

extern "C" void kernel_launch(void* const* d_in, const int* in_sizes, int n_in,
                              void* d_out, int out_size, void* d_ws, size_t ws_size,
                              hipStream_t stream) {
  P p;
  p.x   = (const float*)d_in[0];
  p.y   = (const int*)  d_in[1];
  p.emb = (const float*)d_in[2];
  p.wih = (const float*)d_in[3];
  p.whh = (const float*)d_in[4];
  p.bih = (const float*)d_in[5];
  p.bhh = (const float*)d_in[6];
  p.cw  = (const float*)d_in[7];
  p.cb  = (const float*)d_in[8];
  p.aw  = (const float*)d_in[9];
  p.ab  = (const float*)d_in[10];
  p.fw  = (const float*)d_in[11];
  p.fb  = (const float*)d_in[12];
  p.out = (float*)d_out;
  p.ctrl = (int*)d_ws;

  // layout: 16KB ctrl | float region (rot buffers + partials) | fp16 x-copy
  auto flcount = [](int D) -> size_t {
    return (size_t)2*D*BB*HH + (size_t)D*BB*AXP + (size_t)BB*TT + 512 + (size_t)BB*8*HH;
  };
  size_t need_deep = 16384 + 4*flcount(NSTEP) + (size_t)2*BB*TT*HH;
  p.deep = (ws_size >= need_deep) ? 1 : 0;
  int D = p.deep ? NSTEP : 4;
  p.fws = (float*)((char*)d_ws + 16384);
  p.xh  = (_Float16*)((char*)d_ws + 16384 + 4*flcount(D));

  // zero flag/ticket/counter control region
  hipMemsetAsync(d_ws, 0, 16384, stream);

  void* args[] = { &p };
  hipError_t err = hipLaunchCooperativeKernel((const void*)seq2seq_kernel,
                                              dim3(NBLK), dim3(NTHR), args, 0, stream);
  if (err != hipSuccess) {
    seq2seq_kernel<<<dim3(NBLK), dim3(NTHR), 0, stream>>>(p);
  }
}

// Round 7
// 2755.309 us; speedup vs baseline: 1.2203x; 1.2203x over previous
//
#include <hip/hip_runtime.h>

#define BB 32
#define TT 400
#define HH 512
#define NSTEP 100
#define VO 511
#define LSEQ 101
#define NBLK 256
#define NTHR 512
#define AOFF (BB*NSTEP*VO)
#define AXP 416   // per-b ax stride (128B multiple)
#define DD 2      // rotation depth: shallow (L2-budget), uncached reads
#define AG __HIP_MEMORY_SCOPE_AGENT

typedef float f4 __attribute__((ext_vector_type(4)));
typedef _Float16 hf8 __attribute__((ext_vector_type(8)));
typedef _Float16 v2h __attribute__((ext_vector_type(2)));

#if defined(__has_builtin)
#if __has_builtin(__builtin_amdgcn_fdot2)
#define HAVE_FDOT2 1
#endif
#endif
#ifdef HAVE_FDOT2
#define FDOT2(w, a, c) __builtin_amdgcn_fdot2((w), (a), (c), false)
#else
#define FDOT2(w, a, c) fmaf((float)(w)[0], (float)(a)[0], fmaf((float)(w)[1], (float)(a)[1], (c)))
#endif

struct P {
  const float* x; const int* y; const float* emb;
  const float* wih; const float* whh; const float* bih; const float* bhh;
  const float* cw; const float* cb; const float* aw; const float* ab;
  const float* fw; const float* fb;
  float* out; int* ctrl; float* fws; _Float16* xh;
};

__device__ __forceinline__ float wredsum(float v) {
#pragma unroll
  for (int d = 1; d < 64; d <<= 1) v += __shfl_xor(v, d, 64);
  return v;
}

__device__ __forceinline__ void dot4f(float& acc, f4 wv, f4 av) {
  acc = fmaf(wv.x, av.x, fmaf(wv.y, av.y, fmaf(wv.z, av.z, fmaf(wv.w, av.w, acc))));
}

// uncached (coherence-point) ops for all cross-block data / flags
__device__ __forceinline__ float gld(const float* q) {
  return __hip_atomic_load(q, __ATOMIC_RELAXED, AG);
}
__device__ __forceinline__ void gst(float* q, float v) {
  __hip_atomic_store(q, v, __ATOMIC_RELAXED, AG);
}

__global__ __launch_bounds__(NTHR, 2) void seq2seq_kernel(P p) {
  const int tid  = threadIdx.x;
  const int lane = tid & 63;
  const int wave = tid >> 6;
  const int blk  = blockIdx.x;
  const int sb    = blk >> 3;   // score: batch
  const int tch   = blk & 7;
  const int t0    = tch * 50;
  const int btile = blk >> 6;   // phase3: b-tile
  const int hblk  = blk & 63;
  const int bbase = btile * 8;
  const int hg    = hblk * 8 + wave;
  const int h0s   = lane * 8;

  __shared__ __align__(16) float smem[12288];   // 48 KB unioned arena
  float* axs  = smem;                 // [68]        (score)
  v2h*   axp  = (v2h*)(smem + 80);    // [2][34]     (score, fp16 pairs)
  float* accS = smem + 256;           // [8][512]    (score)
  float* mS   = smem + 256 + 4096;    // [8]
  float* lS   = mS + 8;               // [8]
  float* Avec = smem;                 // [8][1024]   (phase3)
  float* Bvec = smem + 8192;          // [8][512]    (phase3)
  __shared__ int combf;

  float* hxr_buf = p.fws;                              // [DD][BB][HH]
  float* sxr_buf = hxr_buf + (size_t)DD*BB*HH;         // [DD][BB][HH]
  float* axr_buf = sxr_buf + (size_t)DD*BB*HH;         // [DD][BB][AXP]
  float* scg  = axr_buf + (size_t)DD*BB*AXP;           // [BB][TT]
  float* pm   = scg + BB*TT;                           // [BB*8]
  float* pl   = pm + 256;
  float* pacc = pl + 256;                              // [BB][8][HH]

  int* arrv  = p.ctrl;            // ticket[b] at [b*16]
  int* fcomb = p.ctrl + 1024;     // combine flag[b] at [1024+b*16] (monotonic = s+1)
  int* c3    = p.ctrl + 2048;     // phase3 counter[btile] (monotonic)

  // ---- persistent conv/attn weights: taps packed to fp16 pairs (64 VGPRs) ----
  v2h cwp[8][8];
  float cbr[8], awr[8];
#pragma unroll
  for (int j = 0; j < 8; ++j) {
    int h = h0s + j;
    cbr[j] = p.cb[h];
    awr[j] = p.aw[h];
#pragma unroll
    for (int mm = 0; mm < 8; ++mm) {
      float w0 = p.cw[h*15 + 2*mm];
      float w1 = (2*mm+1 < 15) ? p.cw[h*15 + 2*mm + 1] : 0.f;
      cwp[j][mm] = v2h{(_Float16)w0, (_Float16)w1};
    }
  }
  const float atb = p.ab[0];

  // ---- one-time fp16 x-copy (keeps per-XCD working set < 4MB L2) ----
  {
#pragma unroll
    for (int it = 0; it < 7; ++it) {
      const bool valid = (it < 6) || (wave < 2);
      if (valid) {
        const int t = t0 + wave + it*8;
        const float* xp = p.x + ((size_t)sb*TT + t)*HH + h0s;
        f4 x0 = ((const f4*)xp)[0], x1 = ((const f4*)xp)[1];
        hf8 xv;
        xv[0]=(_Float16)x0.x; xv[1]=(_Float16)x0.y; xv[2]=(_Float16)x0.z; xv[3]=(_Float16)x0.w;
        xv[4]=(_Float16)x1.x; xv[5]=(_Float16)x1.y; xv[6]=(_Float16)x1.z; xv[7]=(_Float16)x1.w;
        *(hf8*)(p.xh + ((size_t)sb*TT + t)*HH + h0s) = xv;
      }
    }
    __syncthreads();
  }

  auto spin_ge = [&](int* addr, unsigned target) {
    while (__hip_atomic_load((unsigned*)addr, __ATOMIC_RELAXED, AG) < target)
      __builtin_amdgcn_s_sleep(1);
  };

  // ---- phase3(s): FC(s) + GRU producing hx[s+1]; gated on combine flags ----
  auto phase3 = [&](int s) {
    const bool dofc  = (s >= 0);
    const bool dogru = (s < NSTEP - 1);
    if (s >= 0) {
      if (tid < 8) spin_ge(&fcomb[(bbase + tid)*16], (unsigned)(s+1));
      __syncthreads();
    }
    const int sc_ = (s < 0) ? 0 : s;
    const float* hx_s = hxr_buf + (size_t)(sc_ % DD)*BB*HH;
    const float* sx_s = sxr_buf + (size_t)(sc_ % DD)*BB*HH;
    // batched staging gather: 16 independent uncached loads in flight
    float hxv[8], sxv[8];
    if (dofc) {
#pragma unroll
      for (int b8 = 0; b8 < 8; ++b8) hxv[b8] = gld(hx_s + (size_t)(bbase+b8)*HH + tid);
#pragma unroll
      for (int b8 = 0; b8 < 8; ++b8) sxv[b8] = gld(sx_s + (size_t)(bbase+b8)*HH + tid);
    } else {
#pragma unroll
      for (int b8 = 0; b8 < 8; ++b8) { hxv[b8] = 0.f; sxv[b8] = 0.f; }
    }
    if (dofc) {
#pragma unroll
      for (int b8 = 0; b8 < 8; ++b8) Bvec[b8*512 + tid] = hxv[b8] + sxv[b8];
    }
    if (dogru) {
#pragma unroll
      for (int b8 = 0; b8 < 8; ++b8) {
        const int yb = p.y[(bbase+b8)*LSEQ + (s+1)];
        Avec[b8*1024 + tid]       = p.emb[(size_t)yb*HH + tid] + sxv[b8];
        Avec[b8*1024 + 512 + tid] = hxv[b8];
      }
    }
    __syncthreads();
    if (dofc && hg < VO) {
      const float* fr = p.fw + (size_t)hg*HH;
      f4 fw0 = *(const f4*)(fr + lane*4);
      f4 fw1 = *(const f4*)(fr + lane*4 + 256);
      float fbv = p.fb[hg];
#pragma unroll 1
      for (int b8 = 0; b8 < 8; ++b8) {
        f4 b0 = *(const f4*)(&Bvec[b8*512 + lane*4]);
        f4 b1 = *(const f4*)(&Bvec[b8*512 + lane*4 + 256]);
        float d = 0.f;
        dot4f(d, fw0, b0); dot4f(d, fw1, b1);
        d = wredsum(d);
        if (lane == 0)
          p.out[(size_t)(bbase+b8)*NSTEP*VO + (size_t)s*VO + hg] = d + fbv;
      }
    }
    if (dogru) {
      const int half = lane >> 5, l5 = lane & 31;
      const float* base1 = half ? p.whh : p.wih;
      const float* r1 = base1 + (size_t)hg*HH;
      const float* r2 = base1 + (size_t)(512+hg)*HH;
      const float* r3 = base1 + (size_t)(1024+hg)*HH;
      f4 wr_[4], wz_[4], wn_[4];
#pragma unroll
      for (int q = 0; q < 4; ++q) {
        const int off = l5*4 + q*128;
        wr_[q] = *(const f4*)(r1 + off);
        wz_[q] = *(const f4*)(r2 + off);
        wn_[q] = *(const f4*)(r3 + off);
      }
      const float br  = p.bih[hg] + p.bhh[hg];
      const float bz  = p.bih[512+hg] + p.bhh[512+hg];
      const float bin = p.bih[1024+hg];
      const float bhn = p.bhh[1024+hg];
      float* hx_n = hxr_buf + (size_t)((s+1) % DD)*BB*HH;
#pragma unroll 1
      for (int b8 = 0; b8 < 8; ++b8) {
        f4 a0 = *(const f4*)(&Avec[b8*1024 + half*512 + l5*4]);
        f4 a1 = *(const f4*)(&Avec[b8*1024 + half*512 + l5*4 + 128]);
        f4 a2 = *(const f4*)(&Avec[b8*1024 + half*512 + l5*4 + 256]);
        f4 a3 = *(const f4*)(&Avec[b8*1024 + half*512 + l5*4 + 384]);
        float d1 = 0.f, d2 = 0.f, d3 = 0.f;
        dot4f(d1, wr_[0], a0); dot4f(d1, wr_[1], a1); dot4f(d1, wr_[2], a2); dot4f(d1, wr_[3], a3);
        dot4f(d2, wz_[0], a0); dot4f(d2, wz_[1], a1); dot4f(d2, wz_[2], a2); dot4f(d2, wz_[3], a3);
        dot4f(d3, wn_[0], a0); dot4f(d3, wn_[1], a1); dot4f(d3, wn_[2], a2); dot4f(d3, wn_[3], a3);
#pragma unroll
        for (int dd = 1; dd <= 32; dd <<= 1) { d1 += __shfl_xor(d1, dd, 64); d2 += __shfl_xor(d2, dd, 64); }
#pragma unroll
        for (int dd = 1; dd <= 16; dd <<= 1) d3 += __shfl_xor(d3, dd, 64);
        float d3o = __shfl_xor(d3, 32, 64);
        float i_n = half ? d3o : d3;
        float h_n = half ? d3  : d3o;
        float rg = 1.f / (1.f + __expf(-(d1 + br)));
        float zg = 1.f / (1.f + __expf(-(d2 + bz)));
        float na = (i_n + bin) + rg * (h_n + bhn);
        float e2 = __expf(2.f * na);
        float nn = 1.f - 2.f / (e2 + 1.f);
        float hold = Avec[b8*1024 + 512 + hg];
        float hnew = (1.f - zg) * nn + zg * hold;
        if (lane == 0) gst(&hx_n[(size_t)(bbase+b8)*HH + hg], hnew);
      }
    }
    __syncthreads();
    if (tid == 0 && s < NSTEP - 1) {
      __builtin_amdgcn_s_waitcnt(0);   // drain hx writes before counter
      __hip_atomic_fetch_add((unsigned*)&c3[btile*16], 1u, __ATOMIC_RELAXED, AG);
    }
  };

  // ---- score(s): gated on per-btile phase3 counter ----
  auto score = [&](int s) {
    if (tid == 0) spin_ge(&c3[btile*16], (unsigned)(64*(s+1)));
    __syncthreads();
    const float* hx_s = hxr_buf + (size_t)(s % DD)*BB*HH;
    if (s > 0) {
      const float* ax_p = axr_buf + (size_t)((s-1) % DD)*BB*AXP + (size_t)sb*AXP;
      if (tid < 68) {
        int tg = t0 - 8 + tid;
        axs[tid] = (tg >= 0 && tg < TT) ? gld(ax_p + tg) : 0.f;
      }
      __syncthreads();
      // pack fp16 pair arrays: phase0 = (ax[2m],ax[2m+1]); phase1 = (ax[2m+1],ax[2m+2])
      if (tid < 34) {
        axp[tid] = v2h{(_Float16)axs[2*tid], (_Float16)axs[2*tid+1]};
      } else if (tid >= 64 && tid < 98) {
        int mm = tid - 64;
        float a1 = (2*mm+2 < 68) ? axs[2*mm+2] : 0.f;
        axp[34 + mm] = v2h{(_Float16)axs[2*mm+1], (_Float16)a1};
      }
      __syncthreads();
    }
    const float* hxp = hx_s + (size_t)sb*HH + h0s;
    float hxr[8];
#pragma unroll
    for (int j = 0; j < 8; ++j) hxr[j] = gld(hxp + j);
    float m = -1e30f, l = 0.f;
    float acc[8];
#pragma unroll
    for (int j = 0; j < 8; ++j) acc[j] = 0.f;
#pragma unroll 2
    for (int t = t0 + wave; t < t0 + 50; t += 8) {
      hf8 xv = *(const hf8*)(p.xh + ((size_t)sb*TT + t)*HH + h0s);
      float xr[8];
#pragma unroll
      for (int j = 0; j < 8; ++j) xr[j] = (float)xv[j];
      float cc[8];
      if (s > 0) {
        const int li0 = (t - t0) + 1;   // window = axs[li0 .. li0+14]
        const v2h* ap = axp + ((li0 & 1) ? (34 + ((li0-1) >> 1)) : (li0 >> 1));
        v2h av[8];
#pragma unroll
        for (int mm = 0; mm < 8; ++mm) av[mm] = ap[mm];
#pragma unroll
        for (int j = 0; j < 8; ++j) {
          float a = cbr[j];
#pragma unroll
          for (int mm = 0; mm < 8; ++mm) a = FDOT2(cwp[j][mm], av[mm], a);
          cc[j] = a;
        }
      } else {
#pragma unroll
        for (int j = 0; j < 8; ++j) cc[j] = 0.f;
      }
      float part = 0.f;
#pragma unroll
      for (int j = 0; j < 8; ++j) {
        float vv = xr[j] + hxr[j] + cc[j];
        vv = fmaxf(vv, 0.f);
        part = fmaf(vv, awr[j], part);
      }
      part = wredsum(part);
      float st = part + atb;
      if (lane == 0) gst(&scg[sb*TT + t], st);
      float mn  = fmaxf(m, st);
      float scl = __expf(m - mn);
      float pe  = __expf(st - mn);
      l = l * scl + pe;
#pragma unroll
      for (int j = 0; j < 8; ++j) acc[j] = fmaf(acc[j], scl, pe * xr[j]);
      m = mn;
    }
    {
      f4 s0 = {acc[0],acc[1],acc[2],acc[3]}, s1_ = {acc[4],acc[5],acc[6],acc[7]};
      ((f4*)(&accS[wave*512 + h0s]))[0] = s0;
      ((f4*)(&accS[wave*512 + h0s]))[1] = s1_;
      if (lane == 0) { mS[wave] = m; lS[wave] = l; }
    }
    __syncthreads();
    float mb = mS[0];
#pragma unroll
    for (int w = 1; w < 8; ++w) mb = fmaxf(mb, mS[w]);
    float lb = 0.f, ew[8];
#pragma unroll
    for (int w = 0; w < 8; ++w) { ew[w] = __expf(mS[w] - mb); lb = fmaf(ew[w], lS[w], lb); }
    float ab_ = 0.f;
#pragma unroll
    for (int w = 0; w < 8; ++w) ab_ = fmaf(ew[w], accS[w*512 + tid], ab_);
    gst(&pacc[(size_t)(sb*8 + tch)*HH + tid], ab_);
    if (tid == 0) { gst(&pm[sb*8+tch], mb); gst(&pl[sb*8+tch], lb); }
    __syncthreads();
    if (tid == 0) {
      __builtin_amdgcn_s_waitcnt(0);   // drain partials before ticket
      unsigned old = __hip_atomic_fetch_add((unsigned*)&arrv[sb*16], 1u, __ATOMIC_RELAXED, AG);
      combf = (old == 7u) ? 1 : 0;
      if (old == 7u)
        __hip_atomic_store((unsigned*)&arrv[sb*16], 0u, __ATOMIC_RELAXED, AG);
    }
    __syncthreads();
    if (combf) {   // owner block: combine -> sx(s), ax(s), aligns
      float pmv[8], plv[8];
#pragma unroll
      for (int c = 0; c < 8; ++c) { pmv[c] = gld(&pm[sb*8+c]); plv[c] = gld(&pl[sb*8+c]); }
      float mm2 = pmv[0];
#pragma unroll
      for (int c = 1; c < 8; ++c) mm2 = fmaxf(mm2, pmv[c]);
      float ls = 0.f, ee[8];
#pragma unroll
      for (int c = 0; c < 8; ++c) { ee[c] = __expf(pmv[c] - mm2); ls = fmaf(ee[c], plv[c], ls); }
      float inv = 1.f / ls;
      float sv = 0.f;
#pragma unroll
      for (int c = 0; c < 8; ++c) sv = fmaf(ee[c], gld(&pacc[(size_t)(sb*8+c)*HH + tid]), sv);
      gst(sxr_buf + (size_t)(s % DD)*BB*HH + (size_t)sb*HH + tid, sv * inv);
      float* ax_w = axr_buf + (size_t)(s % DD)*BB*AXP + (size_t)sb*AXP;
      for (int t = tid; t < TT; t += NTHR) {
        float a = __expf(gld(&scg[sb*TT + t]) - mm2) * inv;
        gst(ax_w + t, a);
        p.out[AOFF + (size_t)sb*NSTEP*TT + (size_t)s*TT + t] = a;
      }
      __syncthreads();
      if (tid == 0) {
        __builtin_amdgcn_s_waitcnt(0); // drain sx/ax before flag
        __hip_atomic_store((unsigned*)&fcomb[sb*16], (unsigned)(s+1), __ATOMIC_RELAXED, AG);
      }
    }
  };

  // ---- main sequence: flag-gated pipeline, no global barrier ----
  phase3(-1);   // GRU step 0 (hx=0, sx=0) -> hx_rot[0], c3 += 1
  for (int s = 0; s < NSTEP; ++s) {
    score(s);
    phase3(s);
  }
}

extern "C" void kernel_launch(void* const* d_in, const int* in_sizes, int n_in,
                              void* d_out, int out_size, void* d_ws, size_t ws_size,
                              hipStream_t stream) {
  P p;
  p.x   = (const float*)d_in[0];
  p.y   = (const int*)  d_in[1];
  p.emb = (const float*)d_in[2];
  p.wih = (const float*)d_in[3];
  p.whh = (const float*)d_in[4];
  p.bih = (const float*)d_in[5];
  p.bhh = (const float*)d_in[6];
  p.cw  = (const float*)d_in[7];
  p.cb  = (const float*)d_in[8];
  p.aw  = (const float*)d_in[9];
  p.ab  = (const float*)d_in[10];
  p.fw  = (const float*)d_in[11];
  p.fb  = (const float*)d_in[12];
  p.out = (float*)d_out;
  p.ctrl = (int*)d_ws;

  // floats: hx(2)+sx(2) rot | ax rot | scg | pm/pl | pacc
  size_t flcount = (size_t)2*DD*BB*HH + (size_t)DD*BB*AXP + (size_t)BB*TT + 512 + (size_t)BB*8*HH;
  p.fws = (float*)((char*)d_ws + 16384);
  p.xh  = (_Float16*)((char*)d_ws + 16384 + 4*flcount);

  // zero flag/ticket/counter control region
  hipMemsetAsync(d_ws, 0, 16384, stream);

  void* args[] = { &p };
  hipError_t err = hipLaunchCooperativeKernel((const void*)seq2seq_kernel,
                                              dim3(NBLK), dim3(NTHR), args, 0, stream);
  if (err != hipSuccess) {
    seq2seq_kernel<<<dim3(NBLK), dim3(NTHR), 0, stream>>>(p);
  }
}

// Round 9
// 2574.390 us; speedup vs baseline: 1.3060x; 1.0703x over previous
//
#include <hip/hip_runtime.h>

#define BB 32
#define TT 400
#define HH 512
#define NSTEP 100
#define VO 511
#define LSEQ 101
#define NBLK 256
#define NTHR 512
#define AOFF (BB*NSTEP*VO)
#define AXP 416
#define AG __HIP_MEMORY_SCOPE_AGENT
#define SPIN_CAP 20000000u   // converts any deadlock into a wrong answer, not a hang

typedef float f4 __attribute__((ext_vector_type(4)));
typedef _Float16 v2h __attribute__((ext_vector_type(2)));
typedef _Float16 v8h __attribute__((ext_vector_type(8)));

#if defined(__has_builtin)
#if __has_builtin(__builtin_amdgcn_fdot2)
#define HAVE_FDOT2 1
#endif
#endif
#ifdef HAVE_FDOT2
#define FDOT2(w, a, c) __builtin_amdgcn_fdot2((w), (a), (c), false)
#else
#define FDOT2(w, a, c) fmaf((float)(w)[0], (float)(a)[0], fmaf((float)(w)[1], (float)(a)[1], (c)))
#endif

struct P {
  const float* x; const int* y; const float* emb;
  const float* wih; const float* whh; const float* bih; const float* bhh;
  const float* cw; const float* cb; const float* aw; const float* ab;
  const float* fw; const float* fb;
  float* out; int* ctrl; float* fws;
};

__device__ __forceinline__ float wredsum(float v) {
#pragma unroll
  for (int d = 1; d < 64; d <<= 1) v += __shfl_xor(v, d, 64);
  return v;
}
__device__ __forceinline__ void dot4f(float& acc, f4 wv, f4 av) {
  acc = fmaf(wv.x, av.x, fmaf(wv.y, av.y, fmaf(wv.z, av.z, fmaf(wv.w, av.w, acc))));
}
// uncached (IC coherence point) ops for cross-block data / flags
__device__ __forceinline__ float gld(const float* q) {
  return __hip_atomic_load(q, __ATOMIC_RELAXED, AG);
}
__device__ __forceinline__ void gst(float* q, float v) {
  __hip_atomic_store(q, v, __ATOMIC_RELAXED, AG);
}

__global__ __launch_bounds__(NTHR, 2) void seq2seq_kernel(P p) {
  const int tid  = threadIdx.x;
  const int lane = tid & 63;
  const int wave = tid >> 6;
  const int blk  = blockIdx.x;
  // team = 8 blocks per batch b; this block owns t-chunk [t0,t0+50) for the
  // score phase and h/row slice [hb,hb+64) for GRU/FC. Cross-block traffic is
  // team-local; gates are two 8-participant monotonic counters per step.
  const int b   = blk >> 3;
  const int tch = blk & 7;
  const int t0  = tch * 50;
  const int hb  = tch * 64;
  const int h0s = lane * 8;

  // ---- LDS (~61 KB static) ----
  __shared__ __align__(16) _Float16 xhL[50*512];   // this block's x-chunk (fp16), whole launch
  __shared__ __align__(16) float accS[1024];       // 2-slot, 4-phase wave merge
  __shared__ __align__(16) float hxL[512];         // hx(s), fp32
  __shared__ __align__(16) float sxL[512];         // sx(s), fp32
  __shared__ __align__(16) float ixL[512];         // emb + sx, fp32
  __shared__ float stL[56];
  __shared__ float axs[68];
  __shared__ __align__(8) v2h axp[68];             // conv fp16 pair arrays (2 phases)
  __shared__ float mS[8], lS[8], pmL[8], plL[8];

  float* hx_rot = p.fws;                       // [2][BB][HH]
  float* ax_rot = hx_rot + 2*BB*HH;            // [2][BB][AXP]
  float* pm     = ax_rot + 2*BB*AXP;           // [BB*8]
  float* pl     = pm + 256;
  float* pacc   = pl + 256;                    // [BB][8][HH]

  int* arrv = p.ctrl;               // score-partial counter[b] at [b*16] (monotonic)
  int* hxc  = p.ctrl + 1024;        // gru counter[b] at [1024+b*16]     (monotonic)

  auto spin_ge = [&](int* addr, unsigned target) {
    unsigned it = 0;
    while (__hip_atomic_load((unsigned*)addr, __ATOMIC_RELAXED, AG) < target) {
      __builtin_amdgcn_s_sleep(1);
      if (++it > SPIN_CAP) break;   // degrade to wrong answer, never hang
    }
  };

  // ---- persistent conv/attn weights (fp16 pairs in VGPRs) ----
  v2h cwp[8][8]; float cbr[8], awr[8];
#pragma unroll
  for (int j = 0; j < 8; ++j) {
    int h = h0s + j;
    cbr[j] = p.cb[h]; awr[j] = p.aw[h];
#pragma unroll
    for (int mm = 0; mm < 8; ++mm) {
      float w0 = p.cw[h*15 + 2*mm];
      float w1 = (2*mm+1 < 15) ? p.cw[h*15 + 2*mm + 1] : 0.f;
      cwp[j][mm] = v2h{(_Float16)w0, (_Float16)w1};
    }
  }
  const float atb = p.ab[0];

  // ---- one-time: x chunk -> LDS fp16 (x never read from global again) ----
  for (int i = 0; i < 50; ++i)
    xhL[i*512 + tid] = (_Float16)p.x[((size_t)b*TT + t0 + i)*HH + tid];
  hxL[tid] = 0.f;
  {
    const int yb = p.y[b*LSEQ + 0];
    ixL[tid] = p.emb[(size_t)yb*HH + tid];   // first step: ix = emb, no sx
  }
  __syncthreads();

  // ---- GRU for this block's 64 h: consumes ixL/hxL, writes hx(s+1), bumps hxc ----
  auto gru_step = [&](int s) {
    const int half = lane >> 5, l5 = lane & 31;
    const float* wb_ = half ? p.whh : p.wih;
    const float* ap  = half ? hxL : ixL;
    float* hx_n = hx_rot + (size_t)((unsigned)(s+1) & 1)*BB*HH + (size_t)b*HH;
    // conflict-free LDS slices: lane covers k in {l5*4 + q*128}
    f4 av[4];
#pragma unroll
    for (int q = 0; q < 4; ++q) av[q] = *(const f4*)(ap + l5*4 + q*128);
#pragma unroll 1
    for (int j = 0; j < 8; ++j) {
      const int h = hb + wave*8 + j;
      const float* r1 = wb_ + (size_t)h*HH;
      const float* r2 = wb_ + (size_t)(512+h)*HH;
      const float* r3 = wb_ + (size_t)(1024+h)*HH;
      float d1 = 0.f, d2 = 0.f, d3 = 0.f;
#pragma unroll
      for (int q = 0; q < 4; ++q) {
        const int off = l5*4 + q*128;
        dot4f(d1, *(const f4*)(r1 + off), av[q]);
        dot4f(d2, *(const f4*)(r2 + off), av[q]);
        dot4f(d3, *(const f4*)(r3 + off), av[q]);
      }
#pragma unroll
      for (int dd = 1; dd <= 16; dd <<= 1) {
        d1 += __shfl_xor(d1, dd, 64);
        d2 += __shfl_xor(d2, dd, 64);
        d3 += __shfl_xor(d3, dd, 64);
      }
      d1 += __shfl_xor(d1, 32, 64);       // gi_r + gh_r
      d2 += __shfl_xor(d2, 32, 64);       // gi_z + gh_z
      float d3o = __shfl_xor(d3, 32, 64);
      float i_n = half ? d3o : d3;
      float h_n = half ? d3  : d3o;
      float rg = 1.f/(1.f + __expf(-(d1 + p.bih[h] + p.bhh[h])));
      float zg = 1.f/(1.f + __expf(-(d2 + p.bih[512+h] + p.bhh[512+h])));
      float na = (i_n + p.bih[1024+h]) + rg*(h_n + p.bhh[1024+h]);
      float e2 = __expf(2.f*na);
      float nn = 1.f - 2.f/(e2 + 1.f);
      float hnew = (1.f - zg)*nn + zg*hxL[h];
      if (lane == 0) gst(hx_n + h, hnew);
    }
    __syncthreads();
    if (tid == 0) {
      __builtin_amdgcn_s_waitcnt(0);   // drain hx stores before bump
      __hip_atomic_fetch_add((unsigned*)&hxc[b*16], 1u, __ATOMIC_RELAXED, AG);
    }
  };

  gru_step(-1);   // hx(0) from hx=0, ix=emb[y0]

  for (int s = 0; s < NSTEP; ++s) {
    const int par = s & 1;
    // ---- gate A: hx(s) ready (8 team bumps) ----
    if (tid == 0) spin_ge(&hxc[b*16], (unsigned)(8*(s+1)));
    __syncthreads();
    {
      float hv = gld(hx_rot + (size_t)par*BB*HH + (size_t)b*HH + tid);
      if (s > 0 && tid < 68) {
        int tg = t0 - 8 + tid;
        axs[tid] = (tg >= 0 && tg < TT)
                 ? gld(ax_rot + (size_t)((s-1)&1)*BB*AXP + (size_t)b*AXP + tg) : 0.f;
      }
      hxL[tid] = hv;
    }
    __syncthreads();
    if (s > 0) {
      if (tid < 34) axp[tid] = v2h{(_Float16)axs[2*tid], (_Float16)axs[2*tid+1]};
      else if (tid >= 64 && tid < 98) {
        int mm = tid - 64;
        float a1 = (2*mm+2 < 68) ? axs[2*mm+2] : 0.f;
        axp[34+mm] = v2h{(_Float16)axs[2*mm+1], (_Float16)a1};
      }
      __syncthreads();
    }
    // ---- score over own 50 t (x from LDS) ----
    float hxr[8];
#pragma unroll
    for (int j = 0; j < 8; ++j) hxr[j] = hxL[h0s + j];
    float m = -1e30f, l = 0.f, acc[8];
#pragma unroll
    for (int j = 0; j < 8; ++j) acc[j] = 0.f;
#pragma unroll 2
    for (int lt = wave; lt < 50; lt += 8) {
      v8h xv = *(const v8h*)(xhL + lt*512 + h0s);
      float xr[8];
#pragma unroll
      for (int j = 0; j < 8; ++j) xr[j] = (float)xv[j];
      float cc[8];
      if (s > 0) {
        const int li0 = lt + 1;
        const v2h* ap2 = axp + ((li0 & 1) ? (34 + ((li0-1) >> 1)) : (li0 >> 1));
        v2h av2[8];
#pragma unroll
        for (int mm = 0; mm < 8; ++mm) av2[mm] = ap2[mm];
#pragma unroll
        for (int j = 0; j < 8; ++j) {
          float a = cbr[j];
#pragma unroll
          for (int mm = 0; mm < 8; ++mm) a = FDOT2(cwp[j][mm], av2[mm], a);
          cc[j] = a;
        }
      } else {
#pragma unroll
        for (int j = 0; j < 8; ++j) cc[j] = 0.f;
      }
      float part = 0.f;
#pragma unroll
      for (int j = 0; j < 8; ++j) {
        float vv = xr[j] + hxr[j] + cc[j];
        vv = fmaxf(vv, 0.f);
        part = fmaf(vv, awr[j], part);
      }
      part = wredsum(part);
      float st = part + atb;
      if (lane == 0) stL[lt] = st;
      float mn  = fmaxf(m, st);
      float scl = __expf(m - mn);
      float pe  = __expf(st - mn);
      l = l*scl + pe;
#pragma unroll
      for (int j = 0; j < 8; ++j) acc[j] = fmaf(acc[j], scl, pe*xr[j]);
      m = mn;
    }
    if (lane == 0) { mS[wave] = m; lS[wave] = l; }
    __syncthreads();
    float mb = mS[0];
#pragma unroll
    for (int w = 1; w < 8; ++w) mb = fmaxf(mb, mS[w]);
    float lb = 0.f, ew[8];
#pragma unroll
    for (int w = 0; w < 8; ++w) { ew[w] = __expf(mS[w] - mb); lb = fmaf(ew[w], lS[w], lb); }
    // 4-phase wave merge into 2-slot accS
#pragma unroll
    for (int ph = 0; ph < 4; ++ph) {
      if ((wave >> 1) == ph) {
        float* dst = accS + (wave & 1)*512 + h0s;
        if (ph == 0) {
#pragma unroll
          for (int j = 0; j < 8; ++j) dst[j] = ew[wave]*acc[j];
        } else {
#pragma unroll
          for (int j = 0; j < 8; ++j) dst[j] += ew[wave]*acc[j];
        }
      }
      __syncthreads();
    }
    float ab = accS[tid] + accS[512 + tid];
    gst(&pacc[(size_t)(b*8 + tch)*HH + tid], ab);
    if (tid == 0) { gst(&pm[b*8+tch], mb); gst(&pl[b*8+tch], lb); }
    __syncthreads();
    // ---- gate B: all 8 chunk partials in ----
    if (tid == 0) {
      __builtin_amdgcn_s_waitcnt(0);
      __hip_atomic_fetch_add((unsigned*)&arrv[b*16], 1u, __ATOMIC_RELAXED, AG);
      spin_ge(&arrv[b*16], (unsigned)(8*(s+1)));
    }
    __syncthreads();
    // ---- combine (redundant in every team block; sx stays in LDS) ----
    if (tid < 8)       pmL[tid]   = gld(&pm[b*8 + tid]);
    else if (tid < 16) plL[tid-8] = gld(&pl[b*8 + tid - 8]);
    __syncthreads();
    float mm2 = pmL[0];
#pragma unroll
    for (int c = 1; c < 8; ++c) mm2 = fmaxf(mm2, pmL[c]);
    float ls = 0.f, ee[8];
#pragma unroll
    for (int c = 0; c < 8; ++c) { ee[c] = __expf(pmL[c] - mm2); ls = fmaf(ee[c], plL[c], ls); }
    float inv = 1.f / ls;
    float sv = 0.f;
#pragma unroll
    for (int c = 0; c < 8; ++c) sv = fmaf(ee[c], gld(&pacc[(size_t)(b*8+c)*HH + tid]), sv);
    sxL[tid] = sv * inv;
    if (tid < 50) {
      float a = __expf(stL[tid] - mm2) * inv;
      gst(ax_rot + (size_t)par*BB*AXP + (size_t)b*AXP + t0 + tid, a);
      p.out[AOFF + (size_t)b*NSTEP*TT + (size_t)s*TT + t0 + tid] = a;
    }
    __syncthreads();
    if (s < NSTEP-1) {
      const int yb = p.y[b*LSEQ + (s+1)];
      ixL[tid] = p.emb[(size_t)yb*HH + tid] + sxL[tid];
    }
    __syncthreads();
    // ---- FC: own 64 rows, fp32 weights (conflict-free slices lane*4, +256) ----
    {
      f4 b0 = *(const f4*)(hxL + lane*4);
      f4 b1 = *(const f4*)(hxL + lane*4 + 256);
      f4 s0 = *(const f4*)(sxL + lane*4);
      f4 s1 = *(const f4*)(sxL + lane*4 + 256);
      b0 += s0; b1 += s1;
#pragma unroll 1
      for (int j = 0; j < 8; ++j) {
        const int row = hb + wave*8 + j;
        if (row < VO) {
          const float* fr = p.fw + (size_t)row*HH;
          f4 fw0 = *(const f4*)(fr + lane*4);
          f4 fw1 = *(const f4*)(fr + lane*4 + 256);
          float d = 0.f;
          dot4f(d, fw0, b0); dot4f(d, fw1, b1);
          d = wredsum(d);
          if (lane == 0)
            p.out[(size_t)b*NSTEP*VO + (size_t)s*VO + row] = d + p.fb[row];
        }
      }
    }
    // ---- GRU -> hx(s+1) ----
    if (s < NSTEP-1) gru_step(s);
  }
}

extern "C" void kernel_launch(void* const* d_in, const int* in_sizes, int n_in,
                              void* d_out, int out_size, void* d_ws, size_t ws_size,
                              hipStream_t stream) {
  P p;
  p.x   = (const float*)d_in[0];
  p.y   = (const int*)  d_in[1];
  p.emb = (const float*)d_in[2];
  p.wih = (const float*)d_in[3];
  p.whh = (const float*)d_in[4];
  p.bih = (const float*)d_in[5];
  p.bhh = (const float*)d_in[6];
  p.cw  = (const float*)d_in[7];
  p.cb  = (const float*)d_in[8];
  p.aw  = (const float*)d_in[9];
  p.ab  = (const float*)d_in[10];
  p.fw  = (const float*)d_in[11];
  p.fb  = (const float*)d_in[12];
  p.out = (float*)d_out;
  p.ctrl = (int*)d_ws;
  p.fws  = (float*)((char*)d_ws + 16384);

  // zero monotonic counters
  hipMemsetAsync(d_ws, 0, 16384, stream);

  void* args[] = { &p };
  hipError_t err = hipLaunchCooperativeKernel((const void*)seq2seq_kernel,
                                              dim3(NBLK), dim3(NTHR), args, 0, stream);
  if (err != hipSuccess) {
    seq2seq_kernel<<<dim3(NBLK), dim3(NTHR), 0, stream>>>(p);
  }
}

// Round 10
// 2552.900 us; speedup vs baseline: 1.3170x; 1.0084x over previous
//
#include <hip/hip_runtime.h>

#define BB 32
#define TT 400
#define HH 512
#define NSTEP 100
#define VO 511
#define LSEQ 101
#define NBLK 256
#define NTHR 512
#define AOFF (BB*NSTEP*VO)
#define AXP 416
#define AG __HIP_MEMORY_SCOPE_AGENT
#define SPIN_CAP 20000000u   // converts any deadlock into a wrong answer, not a hang

typedef float f4 __attribute__((ext_vector_type(4)));
typedef _Float16 v2h __attribute__((ext_vector_type(2)));
typedef _Float16 v4h __attribute__((ext_vector_type(4)));
typedef _Float16 v8h __attribute__((ext_vector_type(8)));

#if defined(__has_builtin)
#if __has_builtin(__builtin_amdgcn_fdot2)
#define HAVE_FDOT2 1
#endif
#endif
#ifdef HAVE_FDOT2
#define FDOT2(w, a, c) __builtin_amdgcn_fdot2((w), (a), (c), false)
#else
#define FDOT2(w, a, c) fmaf((float)(w)[0], (float)(a)[0], fmaf((float)(w)[1], (float)(a)[1], (c)))
#endif

struct P {
  const float* x; const int* y; const float* emb;
  const float* wih; const float* whh; const float* bih; const float* bhh;
  const float* cw; const float* cb; const float* aw; const float* ab;
  const float* fw; const float* fb;
  float* out; int* ctrl; float* fws; _Float16* w16;
};

__device__ __forceinline__ float wredsum(float v) {
#pragma unroll
  for (int d = 1; d < 64; d <<= 1) v += __shfl_xor(v, d, 64);
  return v;
}
// fp16-weight x fp32-activation partial dot (compiler emits v_fma_mix / cvt+fma)
__device__ __forceinline__ void dot4h(float& acc, v4h wv, f4 av) {
  acc = fmaf((float)wv[0], av.x, fmaf((float)wv[1], av.y,
        fmaf((float)wv[2], av.z, fmaf((float)wv[3], av.w, acc))));
}
// uncached (IC coherence point) ops for cross-block data / flags
__device__ __forceinline__ float gld(const float* q) {
  return __hip_atomic_load(q, __ATOMIC_RELAXED, AG);
}
__device__ __forceinline__ void gst(float* q, float v) {
  __hip_atomic_store(q, v, __ATOMIC_RELAXED, AG);
}
__device__ __forceinline__ void gstu(unsigned* q, unsigned v) {
  __hip_atomic_store(q, v, __ATOMIC_RELAXED, AG);
}

__global__ __launch_bounds__(NTHR, 2) void seq2seq_kernel(P p) {
  const int tid  = threadIdx.x;
  const int lane = tid & 63;
  const int wave = tid >> 6;
  const int blk  = blockIdx.x;
  // team = 8 blocks per batch b; block owns t-chunk [t0,t0+50) (score) and
  // h/row slice [hb,hb+64) (GRU/FC). Gates: two 8-participant counters/step.
  const int b   = blk >> 3;
  const int tch = blk & 7;
  const int t0  = tch * 50;
  const int hb  = tch * 64;
  const int h0s = lane * 8;

  // ---- LDS (~61 KB static, same as R9) ----
  __shared__ __align__(16) _Float16 xhL[50*512];
  __shared__ __align__(16) float accS[1024];
  __shared__ __align__(16) float hxL[512];
  __shared__ __align__(16) float sxL[512];
  __shared__ __align__(16) float ixL[512];
  __shared__ float stL[56];
  __shared__ float axs[68];
  __shared__ __align__(8) v2h axp[68];
  __shared__ float mS[8], lS[8], pmL[8], plL[8];

  float* hx_rot = p.fws;                       // [2][BB][HH]
  float* ax_rot = hx_rot + 2*BB*HH;            // [2][BB][AXP]
  float* pm     = ax_rot + 2*BB*AXP;           // [BB*8]
  float* pl     = pm + 256;
  float* pacc   = pl + 256;                    // [BB][8][HH]
  // shared fp16 weights (3.67 MB -> fits 4MB XCD L2; layout-preserving cast)
  _Float16* wih16 = p.w16;
  _Float16* whh16 = wih16 + 1536*512;
  _Float16* fw16  = whh16 + 1536*512;

  int* arrv  = p.ctrl;               // score-partial counter[b]  (monotonic)
  int* hxc   = p.ctrl + 1024;        // gru counter[b]            (monotonic)
  int* initc = p.ctrl + 2048;        // one-time conversion barrier

  auto spin_ge = [&](int* addr, unsigned target) {
    unsigned it = 0;
    while (__hip_atomic_load((unsigned*)addr, __ATOMIC_RELAXED, AG) < target) {
      __builtin_amdgcn_s_sleep(1);
      if (++it > SPIN_CAP) break;
    }
  };

  // ---- persistent conv/attn weights (fp16 pairs in VGPRs) ----
  v2h cwp[8][8]; float cbr[8], awr[8];
#pragma unroll
  for (int j = 0; j < 8; ++j) {
    int h = h0s + j;
    cbr[j] = p.cb[h]; awr[j] = p.aw[h];
#pragma unroll
    for (int mm = 0; mm < 8; ++mm) {
      float w0 = p.cw[h*15 + 2*mm];
      float w1 = (2*mm+1 < 15) ? p.cw[h*15 + 2*mm + 1] : 0.f;
      cwp[j][mm] = v2h{(_Float16)w0, (_Float16)w1};
    }
  }
  const float atb = p.ab[0];

  // ---- one-time: grid-cooperative fp16 weight conversion (uncached -> IC) ----
  {
    const int gthr = NBLK*NTHR;
    const int gid = blk*NTHR + tid;
    unsigned* dw = (unsigned*)wih16;
    for (int i = gid; i < 393216; i += gthr) {
      v2h v{(_Float16)p.wih[2*i], (_Float16)p.wih[2*i+1]};
      union { v2h h; unsigned u; } c; c.h = v; gstu(dw + i, c.u);
    }
    unsigned* dw2 = (unsigned*)whh16;
    for (int i = gid; i < 393216; i += gthr) {
      v2h v{(_Float16)p.whh[2*i], (_Float16)p.whh[2*i+1]};
      union { v2h h; unsigned u; } c; c.h = v; gstu(dw2 + i, c.u);
    }
    unsigned* dw3 = (unsigned*)fw16;
    for (int i = gid; i < 130816; i += gthr) {
      v2h v{(_Float16)p.fw[2*i], (_Float16)p.fw[2*i+1]};
      union { v2h h; unsigned u; } c; c.h = v; gstu(dw3 + i, c.u);
    }
  }
  // x chunk -> LDS fp16 (x never read from global again)
  for (int i = 0; i < 50; ++i)
    xhL[i*512 + tid] = (_Float16)p.x[((size_t)b*TT + t0 + i)*HH + tid];
  hxL[tid] = 0.f;
  {
    const int yb = p.y[b*LSEQ + 0];
    ixL[tid] = p.emb[(size_t)yb*HH + tid];
  }
  __syncthreads();                 // drains each wave's conversion stores
  if (tid == 0) {
    __builtin_amdgcn_s_waitcnt(0);
    __hip_atomic_fetch_add((unsigned*)initc, 1u, __ATOMIC_RELAXED, AG);
    spin_ge(initc, (unsigned)NBLK);
  }
  __syncthreads();

  // ---- GRU (fp16 weights): consumes ixL/hxL, writes hx(s+1), bumps hxc ----
  auto gru_step = [&](int s) {
    const int half = lane >> 5, l5 = lane & 31;
    const _Float16* wb_ = half ? whh16 : wih16;
    const float* ap  = half ? hxL : ixL;
    float* hx_n = hx_rot + (size_t)((unsigned)(s+1) & 1)*BB*HH + (size_t)b*HH;
    f4 av[4];
#pragma unroll
    for (int q = 0; q < 4; ++q) av[q] = *(const f4*)(ap + l5*4 + q*128);
#pragma unroll 1
    for (int j = 0; j < 8; ++j) {
      const int h = hb + wave*8 + j;
      const _Float16* r1 = wb_ + (size_t)h*HH;
      const _Float16* r2 = wb_ + (size_t)(512+h)*HH;
      const _Float16* r3 = wb_ + (size_t)(1024+h)*HH;
      float d1 = 0.f, d2 = 0.f, d3 = 0.f;
#pragma unroll
      for (int q = 0; q < 4; ++q) {
        const int off = l5*4 + q*128;
        dot4h(d1, *(const v4h*)(r1 + off), av[q]);
        dot4h(d2, *(const v4h*)(r2 + off), av[q]);
        dot4h(d3, *(const v4h*)(r3 + off), av[q]);
      }
#pragma unroll
      for (int dd = 1; dd <= 16; dd <<= 1) {
        d1 += __shfl_xor(d1, dd, 64);
        d2 += __shfl_xor(d2, dd, 64);
        d3 += __shfl_xor(d3, dd, 64);
      }
      d1 += __shfl_xor(d1, 32, 64);
      d2 += __shfl_xor(d2, 32, 64);
      float d3o = __shfl_xor(d3, 32, 64);
      float i_n = half ? d3o : d3;
      float h_n = half ? d3  : d3o;
      float rg = 1.f/(1.f + __expf(-(d1 + p.bih[h] + p.bhh[h])));
      float zg = 1.f/(1.f + __expf(-(d2 + p.bih[512+h] + p.bhh[512+h])));
      float na = (i_n + p.bih[1024+h]) + rg*(h_n + p.bhh[1024+h]);
      float e2 = __expf(2.f*na);
      float nn = 1.f - 2.f/(e2 + 1.f);
      float hnew = (1.f - zg)*nn + zg*hxL[h];
      if (lane == 0) gst(hx_n + h, hnew);
    }
    __syncthreads();
    if (tid == 0) {
      __builtin_amdgcn_s_waitcnt(0);
      __hip_atomic_fetch_add((unsigned*)&hxc[b*16], 1u, __ATOMIC_RELAXED, AG);
    }
  };

  gru_step(-1);   // hx(0) from hx=0, ix=emb[y0]

  for (int s = 0; s < NSTEP; ++s) {
    const int par = s & 1;
    // ---- gate A: hx(s) ready (8 team bumps) ----
    if (tid == 0) spin_ge(&hxc[b*16], (unsigned)(8*(s+1)));
    __syncthreads();
    {
      float hv = gld(hx_rot + (size_t)par*BB*HH + (size_t)b*HH + tid);
      if (s > 0 && tid < 68) {
        int tg = t0 - 8 + tid;
        axs[tid] = (tg >= 0 && tg < TT)
                 ? gld(ax_rot + (size_t)((s-1)&1)*BB*AXP + (size_t)b*AXP + tg) : 0.f;
      }
      hxL[tid] = hv;
    }
    __syncthreads();
    if (s > 0) {
      if (tid < 34) axp[tid] = v2h{(_Float16)axs[2*tid], (_Float16)axs[2*tid+1]};
      else if (tid >= 64 && tid < 98) {
        int mm = tid - 64;
        float a1 = (2*mm+2 < 68) ? axs[2*mm+2] : 0.f;
        axp[34+mm] = v2h{(_Float16)axs[2*mm+1], (_Float16)a1};
      }
      __syncthreads();
    }
    // ---- score over own 50 t (x from LDS) ----
    float hxr[8];
#pragma unroll
    for (int j = 0; j < 8; ++j) hxr[j] = hxL[h0s + j];
    float m = -1e30f, l = 0.f, acc[8];
#pragma unroll
    for (int j = 0; j < 8; ++j) acc[j] = 0.f;
#pragma unroll 2
    for (int lt = wave; lt < 50; lt += 8) {
      v8h xv = *(const v8h*)(xhL + lt*512 + h0s);
      float xr[8];
#pragma unroll
      for (int j = 0; j < 8; ++j) xr[j] = (float)xv[j];
      float cc[8];
      if (s > 0) {
        const int li0 = lt + 1;
        const v2h* ap2 = axp + ((li0 & 1) ? (34 + ((li0-1) >> 1)) : (li0 >> 1));
        v2h av2[8];
#pragma unroll
        for (int mm = 0; mm < 8; ++mm) av2[mm] = ap2[mm];
#pragma unroll
        for (int j = 0; j < 8; ++j) {
          float a = cbr[j];
#pragma unroll
          for (int mm = 0; mm < 8; ++mm) a = FDOT2(cwp[j][mm], av2[mm], a);
          cc[j] = a;
        }
      } else {
#pragma unroll
        for (int j = 0; j < 8; ++j) cc[j] = 0.f;
      }
      float part = 0.f;
#pragma unroll
      for (int j = 0; j < 8; ++j) {
        float vv = xr[j] + hxr[j] + cc[j];
        vv = fmaxf(vv, 0.f);
        part = fmaf(vv, awr[j], part);
      }
      part = wredsum(part);
      float st = part + atb;
      if (lane == 0) stL[lt] = st;
      float mn  = fmaxf(m, st);
      float scl = __expf(m - mn);
      float pe  = __expf(st - mn);
      l = l*scl + pe;
#pragma unroll
      for (int j = 0; j < 8; ++j) acc[j] = fmaf(acc[j], scl, pe*xr[j]);
      m = mn;
    }
    if (lane == 0) { mS[wave] = m; lS[wave] = l; }
    __syncthreads();
    float mb = mS[0];
#pragma unroll
    for (int w = 1; w < 8; ++w) mb = fmaxf(mb, mS[w]);
    float lb = 0.f, ew[8];
#pragma unroll
    for (int w = 0; w < 8; ++w) { ew[w] = __expf(mS[w] - mb); lb = fmaf(ew[w], lS[w], lb); }
#pragma unroll
    for (int ph = 0; ph < 4; ++ph) {
      if ((wave >> 1) == ph) {
        float* dst = accS + (wave & 1)*512 + h0s;
        if (ph == 0) {
#pragma unroll
          for (int j = 0; j < 8; ++j) dst[j] = ew[wave]*acc[j];
        } else {
#pragma unroll
          for (int j = 0; j < 8; ++j) dst[j] += ew[wave]*acc[j];
        }
      }
      __syncthreads();
    }
    float ab = accS[tid] + accS[512 + tid];
    gst(&pacc[(size_t)(b*8 + tch)*HH + tid], ab);
    if (tid == 0) { gst(&pm[b*8+tch], mb); gst(&pl[b*8+tch], lb); }
    __syncthreads();
    // ---- gate B: all 8 chunk partials in ----
    if (tid == 0) {
      __builtin_amdgcn_s_waitcnt(0);
      __hip_atomic_fetch_add((unsigned*)&arrv[b*16], 1u, __ATOMIC_RELAXED, AG);
      spin_ge(&arrv[b*16], (unsigned)(8*(s+1)));
    }
    __syncthreads();
    // ---- combine (redundant in every team block; sx stays in LDS) ----
    if (tid < 8)       pmL[tid]   = gld(&pm[b*8 + tid]);
    else if (tid < 16) plL[tid-8] = gld(&pl[b*8 + tid - 8]);
    __syncthreads();
    float mm2 = pmL[0];
#pragma unroll
    for (int c = 1; c < 8; ++c) mm2 = fmaxf(mm2, pmL[c]);
    float ls = 0.f, ee[8];
#pragma unroll
    for (int c = 0; c < 8; ++c) { ee[c] = __expf(pmL[c] - mm2); ls = fmaf(ee[c], plL[c], ls); }
    float inv = 1.f / ls;
    float sv = 0.f;
#pragma unroll
    for (int c = 0; c < 8; ++c) sv = fmaf(ee[c], gld(&pacc[(size_t)(b*8+c)*HH + tid]), sv);
    sxL[tid] = sv * inv;
    if (tid < 50) {
      float a = __expf(stL[tid] - mm2) * inv;
      gst(ax_rot + (size_t)par*BB*AXP + (size_t)b*AXP + t0 + tid, a);
      p.out[AOFF + (size_t)b*NSTEP*TT + (size_t)s*TT + t0 + tid] = a;
    }
    __syncthreads();
    if (s < NSTEP-1) {
      const int yb = p.y[b*LSEQ + (s+1)];
      ixL[tid] = p.emb[(size_t)yb*HH + tid] + sxL[tid];
    }
    __syncthreads();
    // ---- GRU FIRST (critical path: publishes hx + bump ASAP) ----
    if (s < NSTEP-1) gru_step(s);
    // ---- FC after the bump: off critical path (feeds only p.out) ----
    {
      f4 b0 = *(const f4*)(hxL + lane*4);
      f4 b1 = *(const f4*)(hxL + lane*4 + 256);
      f4 s0 = *(const f4*)(sxL + lane*4);
      f4 s1 = *(const f4*)(sxL + lane*4 + 256);
      b0 += s0; b1 += s1;
#pragma unroll 1
      for (int j = 0; j < 8; ++j) {
        const int row = hb + wave*8 + j;
        if (row < VO) {
          const _Float16* fr = fw16 + (size_t)row*HH;
          float d = 0.f;
          dot4h(d, *(const v4h*)(fr + lane*4), b0);
          dot4h(d, *(const v4h*)(fr + lane*4 + 256), b1);
          d = wredsum(d);
          if (lane == 0)
            p.out[(size_t)b*NSTEP*VO + (size_t)s*VO + row] = d + p.fb[row];
        }
      }
    }
  }
}

extern "C" void kernel_launch(void* const* d_in, const int* in_sizes, int n_in,
                              void* d_out, int out_size, void* d_ws, size_t ws_size,
                              hipStream_t stream) {
  P p;
  p.x   = (const float*)d_in[0];
  p.y   = (const int*)  d_in[1];
  p.emb = (const float*)d_in[2];
  p.wih = (const float*)d_in[3];
  p.whh = (const float*)d_in[4];
  p.bih = (const float*)d_in[5];
  p.bhh = (const float*)d_in[6];
  p.cw  = (const float*)d_in[7];
  p.cb  = (const float*)d_in[8];
  p.aw  = (const float*)d_in[9];
  p.ab  = (const float*)d_in[10];
  p.fw  = (const float*)d_in[11];
  p.fb  = (const float*)d_in[12];
  p.out = (float*)d_out;
  p.ctrl = (int*)d_ws;
  // layout: 16KB ctrl | fws floats (763,904 B) | fp16 weights (3.67 MB)
  size_t flcount = (size_t)2*BB*HH + (size_t)2*BB*AXP + 512 + (size_t)BB*8*HH;
  p.fws = (float*)((char*)d_ws + 16384);
  p.w16 = (_Float16*)((char*)d_ws + 16384 + 4*flcount);

  hipMemsetAsync(d_ws, 0, 16384, stream);

  void* args[] = { &p };
  hipError_t err = hipLaunchCooperativeKernel((const void*)seq2seq_kernel,
                                              dim3(NBLK), dim3(NTHR), args, 0, stream);
  if (err != hipSuccess) {
    seq2seq_kernel<<<dim3(NBLK), dim3(NTHR), 0, stream>>>(p);
  }
}

// Round 11
// 2361.374 us; speedup vs baseline: 1.4238x; 1.0811x over previous
//
#include <hip/hip_runtime.h>

#define BB 32
#define TT 400
#define HH 512
#define NSTEP 100
#define VO 511
#define LSEQ 101
#define NBLK 256
#define NTHR 512
#define AOFF (BB*NSTEP*VO)
#define AXP 416
#define AG __HIP_MEMORY_SCOPE_AGENT
#define SPIN_CAP 20000000u

typedef float f4 __attribute__((ext_vector_type(4)));
typedef _Float16 v2h __attribute__((ext_vector_type(2)));
typedef _Float16 v4h __attribute__((ext_vector_type(4)));
typedef _Float16 v8h __attribute__((ext_vector_type(8)));

#if defined(__has_builtin)
#if __has_builtin(__builtin_amdgcn_fdot2)
#define HAVE_FDOT2 1
#endif
#endif
#ifdef HAVE_FDOT2
#define FDOT2(w, a, c) __builtin_amdgcn_fdot2((w), (a), (c), false)
#else
#define FDOT2(w, a, c) fmaf((float)(w)[0], (float)(a)[0], fmaf((float)(w)[1], (float)(a)[1], (c)))
#endif

struct P {
  const float* x; const int* y; const float* emb;
  const float* wih; const float* whh; const float* bih; const float* bhh;
  const float* cw; const float* cb; const float* aw; const float* ab;
  const float* fw; const float* fb;
  float* out; int* ctrl; float* fws; _Float16* w16;
};

__device__ __forceinline__ float wredsum(float v) {
#pragma unroll
  for (int d = 1; d < 64; d <<= 1) v += __shfl_xor(v, d, 64);
  return v;
}
__device__ __forceinline__ void dot4h(float& acc, v4h wv, f4 av) {
  acc = fmaf((float)wv[0], av.x, fmaf((float)wv[1], av.y,
        fmaf((float)wv[2], av.z, fmaf((float)wv[3], av.w, acc))));
}
__device__ __forceinline__ v4h lo4(v8h v){ return v4h{v[0],v[1],v[2],v[3]}; }
__device__ __forceinline__ v4h hi4(v8h v){ return v4h{v[4],v[5],v[6],v[7]}; }
// uncached (IC coherence point) ops
__device__ __forceinline__ float gld(const float* q) {
  return __hip_atomic_load(q, __ATOMIC_RELAXED, AG);
}
__device__ __forceinline__ void gst(float* q, float v) {
  __hip_atomic_store(q, v, __ATOMIC_RELAXED, AG);
}
__device__ __forceinline__ unsigned gldi(const int* q) {
  return __hip_atomic_load((const unsigned*)q, __ATOMIC_RELAXED, AG);
}
__device__ __forceinline__ void gsti(int* q, unsigned v) {
  __hip_atomic_store((unsigned*)q, v, __ATOMIC_RELAXED, AG);
}
__device__ __forceinline__ void gstu(unsigned* q, unsigned v) {
  __hip_atomic_store(q, v, __ATOMIC_RELAXED, AG);
}

__global__ __launch_bounds__(NTHR, 2) void seq2seq_kernel(P p) {
  const int tid  = threadIdx.x;
  const int lane = tid & 63;
  const int wave = tid >> 6;
  const int blk  = blockIdx.x;
  // team = 8 blocks per batch b; block owns t-chunk [t0,t0+50) (score) and
  // h/row slice [hb,hb+64) (GRU/FC). Gates: per-slot flag stores + parallel
  // poll (NO same-address RMW — those serialize ~800cyc each at the IC).
  const int b   = blk >> 3;
  const int tch = blk & 7;
  const int t0  = tch * 50;
  const int hb  = tch * 64;
  const int h0s = lane * 8;

  // ---- LDS (~61 KB static) ----
  __shared__ __align__(16) _Float16 xhL[50*512];
  __shared__ __align__(16) float accS[1024];
  __shared__ __align__(16) float hxL[512];
  __shared__ __align__(16) float sxL[512];
  __shared__ __align__(16) float ixL[512];
  __shared__ float stL[56];
  __shared__ float axs[68];
  __shared__ __align__(8) v2h axp[68];
  __shared__ float mS[8], lS[8], pmL[8], plL[8];

  float* hx_rot = p.fws;                       // [2][BB][HH]
  float* ax_rot = hx_rot + 2*BB*HH;            // [2][BB][AXP]
  float* pm     = ax_rot + 2*BB*AXP;           // [BB*8]
  float* pl     = pm + 256;
  float* pacc   = pl + 256;                    // [BB][8][HH]
  _Float16* wih16 = p.w16;
  _Float16* whh16 = wih16 + 1536*512;
  _Float16* fw16  = whh16 + 1536*512;

  // flag arrays: 64B-strided slots, monotonic values (never reset)
  int* scf   = p.ctrl;               // [(b*8+c)*16] = s+1 when chunk c's partials ready
  int* hxf   = p.ctrl + 4096;        // [(b*8+c)*16] = s+2 when gru(s) slice done
  int* initc = p.ctrl + 8192;        // one-time conversion barrier (RMW, one-time)
  int* scf_b = scf + b*128;
  int* hxf_b = hxf + b*128;

  // wave-0 parallel poll: lanes 0-7 watch the 8 team slots
  auto wait8 = [&](int* base, unsigned target) {
    if (wave == 0) {
      unsigned it = 0;
      for (;;) {
        unsigned v = target;
        if (lane < 8) v = gldi(base + lane*16);
        if (__ballot(v < target) == 0ull) break;
        __builtin_amdgcn_s_sleep(1);
        if (++it > SPIN_CAP) break;
      }
    }
    __syncthreads();
  };

  // ---- persistent conv/attn weights (fp16 pairs in VGPRs) ----
  v2h cwp[8][8]; float cbr[8], awr[8];
#pragma unroll
  for (int j = 0; j < 8; ++j) {
    int h = h0s + j;
    cbr[j] = p.cb[h]; awr[j] = p.aw[h];
#pragma unroll
    for (int mm = 0; mm < 8; ++mm) {
      float w0 = p.cw[h*15 + 2*mm];
      float w1 = (2*mm+1 < 15) ? p.cw[h*15 + 2*mm + 1] : 0.f;
      cwp[j][mm] = v2h{(_Float16)w0, (_Float16)w1};
    }
  }
  const float atb = p.ab[0];

  // ---- one-time: grid-cooperative fp16 weight conversion (uncached -> IC) ----
  {
    const int gthr = NBLK*NTHR;
    const int gid = blk*NTHR + tid;
    unsigned* dw = (unsigned*)wih16;
    for (int i = gid; i < 393216; i += gthr) {
      v2h v{(_Float16)p.wih[2*i], (_Float16)p.wih[2*i+1]};
      union { v2h h; unsigned u; } c; c.h = v; gstu(dw + i, c.u);
    }
    unsigned* dw2 = (unsigned*)whh16;
    for (int i = gid; i < 393216; i += gthr) {
      v2h v{(_Float16)p.whh[2*i], (_Float16)p.whh[2*i+1]};
      union { v2h h; unsigned u; } c; c.h = v; gstu(dw2 + i, c.u);
    }
    unsigned* dw3 = (unsigned*)fw16;
    for (int i = gid; i < 130816; i += gthr) {
      v2h v{(_Float16)p.fw[2*i], (_Float16)p.fw[2*i+1]};
      union { v2h h; unsigned u; } c; c.h = v; gstu(dw3 + i, c.u);
    }
  }
  for (int i = 0; i < 50; ++i)
    xhL[i*512 + tid] = (_Float16)p.x[((size_t)b*TT + t0 + i)*HH + tid];
  hxL[tid] = 0.f;
  {
    const int yb = p.y[b*LSEQ + 0];
    ixL[tid] = p.emb[(size_t)yb*HH + tid];
  }
  __syncthreads();
  if (tid == 0) {
    __builtin_amdgcn_s_waitcnt(0);
    __hip_atomic_fetch_add((unsigned*)initc, 1u, __ATOMIC_RELAXED, AG);
    unsigned it = 0;
    while (__hip_atomic_load((unsigned*)initc, __ATOMIC_RELAXED, AG) < (unsigned)NBLK) {
      __builtin_amdgcn_s_sleep(2);
      if (++it > SPIN_CAP) break;
    }
  }
  __syncthreads();

  // ---- GRU (fp16 weights, 16B loads): ixL/hxL -> hx(s+1); flag hxf = s+2 ----
  auto gru_step = [&](int s) {
    const int half = lane >> 5, l5 = lane & 31;
    const _Float16* wb_ = half ? whh16 : wih16;
    const float* ap  = half ? hxL : ixL;
    float* hx_n = hx_rot + (size_t)((unsigned)(s+1) & 1)*BB*HH + (size_t)b*HH;
    const int k0 = l5*8;           // k-halves: k0..k0+7 and k0+256..k0+263
    f4 a0 = *(const f4*)(ap + k0);
    f4 a1 = *(const f4*)(ap + k0 + 4);
    f4 a2 = *(const f4*)(ap + k0 + 256);
    f4 a3 = *(const f4*)(ap + k0 + 260);
#pragma unroll 1
    for (int j = 0; j < 8; ++j) {
      const int h = hb + wave*8 + j;
      const _Float16* r1 = wb_ + (size_t)h*HH + k0;
      const _Float16* r2 = wb_ + (size_t)(512+h)*HH + k0;
      const _Float16* r3 = wb_ + (size_t)(1024+h)*HH + k0;
      v8h w1a = *(const v8h*)(r1),       w1b = *(const v8h*)(r1 + 256);
      v8h w2a = *(const v8h*)(r2),       w2b = *(const v8h*)(r2 + 256);
      v8h w3a = *(const v8h*)(r3),       w3b = *(const v8h*)(r3 + 256);
      float d1 = 0.f, d2 = 0.f, d3 = 0.f;
      dot4h(d1, lo4(w1a), a0); dot4h(d1, hi4(w1a), a1);
      dot4h(d1, lo4(w1b), a2); dot4h(d1, hi4(w1b), a3);
      dot4h(d2, lo4(w2a), a0); dot4h(d2, hi4(w2a), a1);
      dot4h(d2, lo4(w2b), a2); dot4h(d2, hi4(w2b), a3);
      dot4h(d3, lo4(w3a), a0); dot4h(d3, hi4(w3a), a1);
      dot4h(d3, lo4(w3b), a2); dot4h(d3, hi4(w3b), a3);
#pragma unroll
      for (int dd = 1; dd <= 16; dd <<= 1) {
        d1 += __shfl_xor(d1, dd, 64);
        d2 += __shfl_xor(d2, dd, 64);
        d3 += __shfl_xor(d3, dd, 64);
      }
      d1 += __shfl_xor(d1, 32, 64);
      d2 += __shfl_xor(d2, 32, 64);
      float d3o = __shfl_xor(d3, 32, 64);
      float i_n = half ? d3o : d3;
      float h_n = half ? d3  : d3o;
      float rg = 1.f/(1.f + __expf(-(d1 + p.bih[h] + p.bhh[h])));
      float zg = 1.f/(1.f + __expf(-(d2 + p.bih[512+h] + p.bhh[512+h])));
      float na = (i_n + p.bih[1024+h]) + rg*(h_n + p.bhh[1024+h]);
      float e2 = __expf(2.f*na);
      float nn = 1.f - 2.f/(e2 + 1.f);
      float hnew = (1.f - zg)*nn + zg*hxL[h];
      if (lane == 0) gst(hx_n + h, hnew);
    }
    __syncthreads();               // drains this block's hx stores
    if (tid == 0) {
      __builtin_amdgcn_s_waitcnt(0);
      gsti(hxf_b + tch*16, (unsigned)(s+2));
    }
  };

  gru_step(-1);   // hx(0): hx=0, ix=emb[y0]; flags hxf = 1

  for (int s = 0; s < NSTEP; ++s) {
    const int par = s & 1;
    // ---- gate A: hx(s) ready in all 8 slices ----
    wait8(hxf_b, (unsigned)(s+1));
    {
      float hv = gld(hx_rot + (size_t)par*BB*HH + (size_t)b*HH + tid);
      if (s > 0 && tid < 68) {
        int tg = t0 - 8 + tid;
        axs[tid] = (tg >= 0 && tg < TT)
                 ? gld(ax_rot + (size_t)((s-1)&1)*BB*AXP + (size_t)b*AXP + tg) : 0.f;
      }
      hxL[tid] = hv;
    }
    __syncthreads();
    if (s > 0) {
      if (tid < 34) axp[tid] = v2h{(_Float16)axs[2*tid], (_Float16)axs[2*tid+1]};
      else if (tid >= 64 && tid < 98) {
        int mm = tid - 64;
        float a1 = (2*mm+2 < 68) ? axs[2*mm+2] : 0.f;
        axp[34+mm] = v2h{(_Float16)axs[2*mm+1], (_Float16)a1};
      }
      __syncthreads();
    }
    // ---- score over own 50 t (x from LDS) ----
    float hxr[8];
#pragma unroll
    for (int j = 0; j < 8; ++j) hxr[j] = hxL[h0s + j];
    float m = -1e30f, l = 0.f, acc[8];
#pragma unroll
    for (int j = 0; j < 8; ++j) acc[j] = 0.f;
#pragma unroll 2
    for (int lt = wave; lt < 50; lt += 8) {
      v8h xv = *(const v8h*)(xhL + lt*512 + h0s);
      float xr[8];
#pragma unroll
      for (int j = 0; j < 8; ++j) xr[j] = (float)xv[j];
      float cc[8];
      if (s > 0) {
        const int li0 = lt + 1;
        const v2h* ap2 = axp + ((li0 & 1) ? (34 + ((li0-1) >> 1)) : (li0 >> 1));
        v2h av2[8];
#pragma unroll
        for (int mm = 0; mm < 8; ++mm) av2[mm] = ap2[mm];
#pragma unroll
        for (int j = 0; j < 8; ++j) {
          float a = cbr[j];
#pragma unroll
          for (int mm = 0; mm < 8; ++mm) a = FDOT2(cwp[j][mm], av2[mm], a);
          cc[j] = a;
        }
      } else {
#pragma unroll
        for (int j = 0; j < 8; ++j) cc[j] = 0.f;
      }
      float part = 0.f;
#pragma unroll
      for (int j = 0; j < 8; ++j) {
        float vv = xr[j] + hxr[j] + cc[j];
        vv = fmaxf(vv, 0.f);
        part = fmaf(vv, awr[j], part);
      }
      part = wredsum(part);
      float st = part + atb;
      if (lane == 0) stL[lt] = st;
      float mn  = fmaxf(m, st);
      float scl = __expf(m - mn);
      float pe  = __expf(st - mn);
      l = l*scl + pe;
#pragma unroll
      for (int j = 0; j < 8; ++j) acc[j] = fmaf(acc[j], scl, pe*xr[j]);
      m = mn;
    }
    if (lane == 0) { mS[wave] = m; lS[wave] = l; }
    __syncthreads();
    float mb = mS[0];
#pragma unroll
    for (int w = 1; w < 8; ++w) mb = fmaxf(mb, mS[w]);
    float lb = 0.f, ew[8];
#pragma unroll
    for (int w = 0; w < 8; ++w) { ew[w] = __expf(mS[w] - mb); lb = fmaf(ew[w], lS[w], lb); }
#pragma unroll
    for (int ph = 0; ph < 4; ++ph) {
      if ((wave >> 1) == ph) {
        float* dst = accS + (wave & 1)*512 + h0s;
        if (ph == 0) {
#pragma unroll
          for (int j = 0; j < 8; ++j) dst[j] = ew[wave]*acc[j];
        } else {
#pragma unroll
          for (int j = 0; j < 8; ++j) dst[j] += ew[wave]*acc[j];
        }
      }
      __syncthreads();
    }
    float ab = accS[tid] + accS[512 + tid];
    gst(&pacc[(size_t)(b*8 + tch)*HH + tid], ab);
    if (tid == 0) { gst(&pm[b*8+tch], mb); gst(&pl[b*8+tch], lb); }
    __syncthreads();                     // drains partial stores (all waves)
    // ---- gate B: publish own flag, prefetch emb under the wait ----
    if (tid == 0) {
      __builtin_amdgcn_s_waitcnt(0);
      gsti(scf_b + tch*16, (unsigned)(s+1));
    }
    float embr = 0.f;
    if (s < NSTEP-1)
      embr = p.emb[(size_t)p.y[b*LSEQ + (s+1)]*HH + tid];   // in flight during gate
    wait8(scf_b, (unsigned)(s+1));
    // ---- combine (redundant in every team block; own chunk from registers) ----
    if (tid < 8)       pmL[tid]   = gld(&pm[b*8 + tid]);
    else if (tid < 16) plL[tid-8] = gld(&pl[b*8 + tid - 8]);
    __syncthreads();
    float mm2 = pmL[0];
#pragma unroll
    for (int c = 1; c < 8; ++c) mm2 = fmaxf(mm2, pmL[c]);
    float ls = 0.f, ee[8];
#pragma unroll
    for (int c = 0; c < 8; ++c) { ee[c] = __expf(pmL[c] - mm2); ls = fmaf(ee[c], plL[c], ls); }
    float inv = 1.f / ls;
    float sv = 0.f;
#pragma unroll
    for (int c = 0; c < 8; ++c) {
      float pv = (c == tch) ? ab : gld(&pacc[(size_t)(b*8+c)*HH + tid]);
      sv = fmaf(ee[c], pv, sv);
    }
    sxL[tid] = sv * inv;
    if (tid < 50) {
      float a = __expf(stL[tid] - mm2) * inv;
      gst(ax_rot + (size_t)par*BB*AXP + (size_t)b*AXP + t0 + tid, a);
      p.out[AOFF + (size_t)b*NSTEP*TT + (size_t)s*TT + t0 + tid] = a;
    }
    __syncthreads();
    if (s < NSTEP-1) ixL[tid] = embr + sxL[tid];
    __syncthreads();
    // ---- GRU first (publishes hx + flag ASAP), FC off the critical path ----
    if (s < NSTEP-1) gru_step(s);
    {
      f4 b0 = *(const f4*)(hxL + lane*8);
      f4 b1 = *(const f4*)(hxL + lane*8 + 4);
      f4 s0 = *(const f4*)(sxL + lane*8);
      f4 s1 = *(const f4*)(sxL + lane*8 + 4);
      b0 += s0; b1 += s1;
#pragma unroll 1
      for (int j = 0; j < 8; ++j) {
        const int row = hb + wave*8 + j;
        if (row < VO) {
          v8h wv = *(const v8h*)(fw16 + (size_t)row*HH + lane*8);
          float d = 0.f;
          dot4h(d, lo4(wv), b0); dot4h(d, hi4(wv), b1);
          d = wredsum(d);
          if (lane == 0)
            p.out[(size_t)b*NSTEP*VO + (size_t)s*VO + row] = d + p.fb[row];
        }
      }
    }
  }
}

extern "C" void kernel_launch(void* const* d_in, const int* in_sizes, int n_in,
                              void* d_out, int out_size, void* d_ws, size_t ws_size,
                              hipStream_t stream) {
  P p;
  p.x   = (const float*)d_in[0];
  p.y   = (const int*)  d_in[1];
  p.emb = (const float*)d_in[2];
  p.wih = (const float*)d_in[3];
  p.whh = (const float*)d_in[4];
  p.bih = (const float*)d_in[5];
  p.bhh = (const float*)d_in[6];
  p.cw  = (const float*)d_in[7];
  p.cb  = (const float*)d_in[8];
  p.aw  = (const float*)d_in[9];
  p.ab  = (const float*)d_in[10];
  p.fw  = (const float*)d_in[11];
  p.fb  = (const float*)d_in[12];
  p.out = (float*)d_out;
  p.ctrl = (int*)d_ws;
  // layout: 48KB flags/ctrl | fws floats | fp16 weights (3.67 MB)
  size_t flcount = (size_t)2*BB*HH + (size_t)2*BB*AXP + 512 + (size_t)BB*8*HH;
  p.fws = (float*)((char*)d_ws + 49152);
  p.w16 = (_Float16*)((char*)d_ws + 49152 + 4*flcount);

  hipMemsetAsync(d_ws, 0, 49152, stream);

  void* args[] = { &p };
  hipError_t err = hipLaunchCooperativeKernel((const void*)seq2seq_kernel,
                                              dim3(NBLK), dim3(NTHR), args, 0, stream);
  if (err != hipSuccess) {
    seq2seq_kernel<<<dim3(NBLK), dim3(NTHR), 0, stream>>>(p);
  }
}

// Round 12
// 1459.129 us; speedup vs baseline: 2.3042x; 1.6183x over previous
//
#include <hip/hip_runtime.h>

#define BB 32
#define TT 400
#define HH 512
#define NSTEP 100
#define VO 511
#define LSEQ 101
#define NBLK 256
#define NTHR 512
#define AOFF (BB*NSTEP*VO)
#define AXP 416
#define AG __HIP_MEMORY_SCOPE_AGENT
#define SPIN_CAP 20000000u

typedef float f4 __attribute__((ext_vector_type(4)));
typedef _Float16 v2h __attribute__((ext_vector_type(2)));
typedef _Float16 v8h __attribute__((ext_vector_type(8)));
typedef unsigned long long ull;

#if defined(__has_builtin)
#if __has_builtin(__builtin_amdgcn_fdot2)
#define HAVE_FDOT2 1
#endif
#endif
#ifdef HAVE_FDOT2
#define FDOT2(w, a, c) __builtin_amdgcn_fdot2((w), (a), (c), false)
#else
#define FDOT2(w, a, c) fmaf((float)(w)[0], (float)(a)[0], fmaf((float)(w)[1], (float)(a)[1], (c)))
#endif

// 8-k fdot2 block: weight v8h vs 4 activation pairs
#define DOT8(acc, wv, p0, p1, p2, p3)                      \
  acc = FDOT2((v2h{(wv)[0],(wv)[1]}), (p0), acc);          \
  acc = FDOT2((v2h{(wv)[2],(wv)[3]}), (p1), acc);          \
  acc = FDOT2((v2h{(wv)[4],(wv)[5]}), (p2), acc);          \
  acc = FDOT2((v2h{(wv)[6],(wv)[7]}), (p3), acc);

struct P {
  const float* x; const int* y; const float* emb;
  const float* wih; const float* whh; const float* bih; const float* bhh;
  const float* cw; const float* cb; const float* aw; const float* ab;
  const float* fw; const float* fb;
  float* out; int* ctrl; float* fws; _Float16* w16;
};

__device__ __forceinline__ float wredsum(float v) {
#pragma unroll
  for (int d = 1; d < 64; d <<= 1) v += __shfl_xor(v, d, 64);
  return v;
}
// uncached (IC coherence point) ops
__device__ __forceinline__ float gld(const float* q) {
  return __hip_atomic_load(q, __ATOMIC_RELAXED, AG);
}
__device__ __forceinline__ void gst(float* q, float v) {
  __hip_atomic_store(q, v, __ATOMIC_RELAXED, AG);
}
__device__ __forceinline__ unsigned gldi(const int* q) {
  return __hip_atomic_load((const unsigned*)q, __ATOMIC_RELAXED, AG);
}
__device__ __forceinline__ void gsti(int* q, unsigned v) {
  __hip_atomic_store((unsigned*)q, v, __ATOMIC_RELAXED, AG);
}
__device__ __forceinline__ void gstll(ull* q, ull v) {
  __hip_atomic_store(q, v, __ATOMIC_RELAXED, AG);
}

__global__ __launch_bounds__(NTHR, 2) void seq2seq_kernel(P p) {
  const int tid  = threadIdx.x;
  const int lane = tid & 63;
  const int wave = tid >> 6;
  const int blk  = blockIdx.x;
  const int b   = blk >> 3;
  const int tch = blk & 7;
  const int t0  = tch * 50;
  const int hb  = tch * 64;
  const int h0s = lane * 8;

  // ---- LDS arena 64,392 B ----
  __shared__ __align__(16) char smem[64392];
  _Float16* xhL = (_Float16*)smem;                 // 51200: x chunk fp16
  float*    hxL = (float*)(smem + 51200);          // 2048: hx(s) fp32
  _Float16* ixh = (_Float16*)(smem + 53248);       // 1024: emb+sx fp16 (doubles as Bh for FC)
  _Float16* hxh = (_Float16*)(smem + 54272);       // 1024: hx fp16
  float*    redu= (float*)(smem + 55296);          // 8192: GRU/FC partials (∪ accS)
  float*    accS= redu;                            // [1024] score merge
  float*    axs = (float*)(smem + 63488);          // 272
  v2h*      axp = (v2h*)(smem + 63760);            // 280
  float*    stL = (float*)(smem + 64040);          // 224
  float*    mS  = (float*)(smem + 64264);          // 32
  float*    lS  = mS + 8; float* pmL = mS + 16; float* plL = mS + 24;

  float* hx_rot = p.fws;                       // [2][BB][HH]
  float* ax_rot = hx_rot + 2*BB*HH;            // [2][BB][AXP]
  float* pm     = ax_rot + 2*BB*AXP;           // [BB*8]
  float* pl     = pm + 256;
  float* pacc   = pl + 256;                    // [BB][8][HH]
  const v8h* wiT = (const v8h*)p.w16;          // [3][64][512] ih (k-major)
  const v8h* whT = wiT + 98304;                // [3][64][512] hh
  const v8h* fwT = wiT + 196608;               // [64][512]    fc

  int* scf   = p.ctrl;               // score flags [(b*8+c)*16] = s+1
  int* hxf   = p.ctrl + 4096;        // gru flags   [(b*8+c)*16] = s+2
  int* initc = p.ctrl + 8192;
  int* scf_b = scf + b*128;
  int* hxf_b = hxf + b*128;

  auto wait8 = [&](int* base, unsigned target) {
    if (wave == 0) {
      unsigned it = 0;
      for (;;) {
        unsigned v = target;
        if (lane < 8) v = gldi(base + lane*16);
        if (__ballot(v < target) == 0ull) break;
        __builtin_amdgcn_s_sleep(1);
        if (++it > SPIN_CAP) break;
      }
    }
    __syncthreads();
  };

  // ---- persistent conv/attn weights ----
  v2h cwp[8][8]; float cbr[8], awr[8];
#pragma unroll
  for (int j = 0; j < 8; ++j) {
    int h = h0s + j;
    cbr[j] = p.cb[h]; awr[j] = p.aw[h];
#pragma unroll
    for (int mm = 0; mm < 8; ++mm) {
      float w0 = p.cw[h*15 + 2*mm];
      float w1 = (2*mm+1 < 15) ? p.cw[h*15 + 2*mm + 1] : 0.f;
      cwp[j][mm] = v2h{(_Float16)w0, (_Float16)w1};
    }
  }
  const float atb = p.ab[0];

  // ---- one-time: transposed fp16 weight build (k-major, h-contiguous) ----
  {
    const int gthr = NBLK*NTHR;
    const int gid = blk*NTHR + tid;
    auto cvt8 = [&](const float* s8, ull* dst) {
      v8h v;
#pragma unroll
      for (int e = 0; e < 8; ++e) v[e] = (_Float16)s8[e];
      union { v8h h; ull u[2]; } c; c.h = v;
      gstll(dst, c.u[0]); gstll(dst + 1, c.u[1]);
    };
    for (int i = gid; i < 98304; i += gthr) {
      int h = i & 511, kb = (i >> 9) & 63, g = i >> 15;
      cvt8(p.wih + ((size_t)(g*512 + h))*512 + kb*8, (ull*)((v8h*)p.w16 + i));
    }
    for (int i = gid; i < 98304; i += gthr) {
      int h = i & 511, kb = (i >> 9) & 63, g = i >> 15;
      cvt8(p.whh + ((size_t)(g*512 + h))*512 + kb*8, (ull*)((v8h*)p.w16 + 98304 + i));
    }
    for (int i = gid; i < 32768; i += gthr) {
      int h = i & 511, kb = i >> 9;
      ull* dst = (ull*)((v8h*)p.w16 + 196608 + i);
      if (h < VO) cvt8(p.fw + (size_t)h*512 + kb*8, dst);
      else { gstll(dst, 0ull); gstll(dst + 1, 0ull); }
    }
  }
  for (int i = 0; i < 50; ++i)
    xhL[i*512 + tid] = (_Float16)p.x[((size_t)b*TT + t0 + i)*HH + tid];
  hxL[tid] = 0.f;
  hxh[tid] = (_Float16)0.f;
  {
    const int yb = p.y[b*LSEQ + 0];
    ixh[tid] = (_Float16)p.emb[(size_t)yb*HH + tid];
  }
  __syncthreads();
  if (tid == 0) {
    __builtin_amdgcn_s_waitcnt(0);
    __hip_atomic_fetch_add((unsigned*)initc, 1u, __ATOMIC_RELAXED, AG);
    unsigned it = 0;
    while (__hip_atomic_load((unsigned*)initc, __ATOMIC_RELAXED, AG) < (unsigned)NBLK) {
      __builtin_amdgcn_s_sleep(2);
      if (++it > SPIN_CAP) break;
    }
  }
  __syncthreads();

  // ---- GRU k-major: lane=h, wave=k-range; LDS tree reduce (no shfl) ----
  auto gru_step = [&](int s) {
    const int hg = hb + lane;
    const v2h* ixp = (const v2h*)ixh;
    const v2h* hxp = (const v2h*)hxh;
    float pr = 0.f, pz = 0.f, pin = 0.f, phn = 0.f;
#pragma unroll 2
    for (int kb = 0; kb < 8; ++kb) {
      const int kbg = wave*8 + kb;
      const int pb  = kbg*4;
      v2h a0 = ixp[pb], a1 = ixp[pb+1], a2 = ixp[pb+2], a3 = ixp[pb+3];
      v2h c0 = hxp[pb], c1 = hxp[pb+1], c2 = hxp[pb+2], c3 = hxp[pb+3];
      v8h wri = wiT[(0*64 + kbg)*512 + hg];
      v8h wzi = wiT[(1*64 + kbg)*512 + hg];
      v8h wni = wiT[(2*64 + kbg)*512 + hg];
      v8h wrh = whT[(0*64 + kbg)*512 + hg];
      v8h wzh = whT[(1*64 + kbg)*512 + hg];
      v8h wnh = whT[(2*64 + kbg)*512 + hg];
      DOT8(pr,  wri, a0, a1, a2, a3);
      DOT8(pr,  wrh, c0, c1, c2, c3);
      DOT8(pz,  wzi, a0, a1, a2, a3);
      DOT8(pz,  wzh, c0, c1, c2, c3);
      DOT8(pin, wni, a0, a1, a2, a3);
      DOT8(phn, wnh, c0, c1, c2, c3);
    }
    redu[wave*256 +   0 + lane] = pr;
    redu[wave*256 +  64 + lane] = pz;
    redu[wave*256 + 128 + lane] = pin;
    redu[wave*256 + 192 + lane] = phn;
    __syncthreads();
    if (tid < 256) {
      float v = 0.f;
#pragma unroll
      for (int w = 0; w < 8; ++w) v += redu[w*256 + tid];
      redu[tid] = v;            // slot tid only read by this thread before write
    }
    __syncthreads();
    if (tid < 64) {
      const int hh_ = hb + tid;
      float r_  = redu[tid], z_ = redu[64+tid], in_ = redu[128+tid], hn_ = redu[192+tid];
      float rg = 1.f/(1.f + __expf(-(r_ + p.bih[hh_] + p.bhh[hh_])));
      float zg = 1.f/(1.f + __expf(-(z_ + p.bih[512+hh_] + p.bhh[512+hh_])));
      float na = (in_ + p.bih[1024+hh_]) + rg*(hn_ + p.bhh[1024+hh_]);
      float e2 = __expf(2.f*na);
      float nn = 1.f - 2.f/(e2 + 1.f);
      float hnew = (1.f - zg)*nn + zg*hxL[hh_];
      float* hx_n = hx_rot + (size_t)((unsigned)(s+1) & 1)*BB*HH + (size_t)b*HH;
      gst(hx_n + hh_, hnew);
    }
    __syncthreads();            // wave0 drains its stores here
    if (tid == 0) gsti(hxf_b + tch*16, (unsigned)(s+2));
  };

  gru_step(-1);

  for (int s = 0; s < NSTEP; ++s) {
    const int par = s & 1;
    // ---- gate A: hx(s) ready ----
    wait8(hxf_b, (unsigned)(s+1));
    {
      float hv = gld(hx_rot + (size_t)par*BB*HH + (size_t)b*HH + tid);
      if (s > 0 && tid < 68) {
        int tg = t0 - 8 + tid;
        axs[tid] = (tg >= 0 && tg < TT)
                 ? gld(ax_rot + (size_t)((s-1)&1)*BB*AXP + (size_t)b*AXP + tg) : 0.f;
      }
      hxL[tid] = hv;
      hxh[tid] = (_Float16)hv;
    }
    __syncthreads();
    if (s > 0) {
      if (tid < 34) axp[tid] = v2h{(_Float16)axs[2*tid], (_Float16)axs[2*tid+1]};
      else if (tid >= 64 && tid < 98) {
        int mm = tid - 64;
        float a1 = (2*mm+2 < 68) ? axs[2*mm+2] : 0.f;
        axp[34+mm] = v2h{(_Float16)axs[2*mm+1], (_Float16)a1};
      }
      __syncthreads();
    }
    // ---- score over own 50 t ----
    float hxr[8];
#pragma unroll
    for (int j = 0; j < 8; ++j) hxr[j] = hxL[h0s + j];
    float m = -1e30f, l = 0.f, acc[8];
#pragma unroll
    for (int j = 0; j < 8; ++j) acc[j] = 0.f;
#pragma unroll 2
    for (int lt = wave; lt < 50; lt += 8) {
      v8h xv = *(const v8h*)(xhL + lt*512 + h0s);
      float xr[8];
#pragma unroll
      for (int j = 0; j < 8; ++j) xr[j] = (float)xv[j];
      float cc[8];
      if (s > 0) {
        const int li0 = lt + 1;
        const v2h* ap2 = axp + ((li0 & 1) ? (34 + ((li0-1) >> 1)) : (li0 >> 1));
        v2h av2[8];
#pragma unroll
        for (int mm = 0; mm < 8; ++mm) av2[mm] = ap2[mm];
#pragma unroll
        for (int j = 0; j < 8; ++j) {
          float a = cbr[j];
#pragma unroll
          for (int mm = 0; mm < 8; ++mm) a = FDOT2(cwp[j][mm], av2[mm], a);
          cc[j] = a;
        }
      } else {
#pragma unroll
        for (int j = 0; j < 8; ++j) cc[j] = 0.f;
      }
      float part = 0.f;
#pragma unroll
      for (int j = 0; j < 8; ++j) {
        float vv = xr[j] + hxr[j] + cc[j];
        vv = fmaxf(vv, 0.f);
        part = fmaf(vv, awr[j], part);
      }
      part = wredsum(part);
      float st = part + atb;
      if (lane == 0) stL[lt] = st;
      float mn  = fmaxf(m, st);
      float scl = __expf(m - mn);
      float pe  = __expf(st - mn);
      l = l*scl + pe;
#pragma unroll
      for (int j = 0; j < 8; ++j) acc[j] = fmaf(acc[j], scl, pe*xr[j]);
      m = mn;
    }
    if (lane == 0) { mS[wave] = m; lS[wave] = l; }
    __syncthreads();
    float mb = mS[0];
#pragma unroll
    for (int w = 1; w < 8; ++w) mb = fmaxf(mb, mS[w]);
    float lb = 0.f, ew[8];
#pragma unroll
    for (int w = 0; w < 8; ++w) { ew[w] = __expf(mS[w] - mb); lb = fmaf(ew[w], lS[w], lb); }
#pragma unroll
    for (int ph = 0; ph < 4; ++ph) {
      if ((wave >> 1) == ph) {
        float* dst = accS + (wave & 1)*512 + h0s;
        if (ph == 0) {
#pragma unroll
          for (int j = 0; j < 8; ++j) dst[j] = ew[wave]*acc[j];
        } else {
#pragma unroll
          for (int j = 0; j < 8; ++j) dst[j] += ew[wave]*acc[j];
        }
      }
      __syncthreads();
    }
    float ab = accS[tid] + accS[512 + tid];
    gst(&pacc[(size_t)(b*8 + tch)*HH + tid], ab);
    if (tid == 0) { gst(&pm[b*8+tch], mb); gst(&pl[b*8+tch], lb); }
    __syncthreads();                       // all waves drain partial stores
    if (tid == 0) gsti(scf_b + tch*16, (unsigned)(s+1));
    float embr = 0.f;
    if (s < NSTEP-1)
      embr = p.emb[(size_t)p.y[b*LSEQ + (s+1)]*HH + tid];   // in flight during gate
    wait8(scf_b, (unsigned)(s+1));
    // ---- combine (redundant per team block) ----
    if (tid < 8)       pmL[tid]   = gld(&pm[b*8 + tid]);
    else if (tid < 16) plL[tid-8] = gld(&pl[b*8 + tid - 8]);
    __syncthreads();
    float mm2 = pmL[0];
#pragma unroll
    for (int c = 1; c < 8; ++c) mm2 = fmaxf(mm2, pmL[c]);
    float ls = 0.f, ee[8];
#pragma unroll
    for (int c = 0; c < 8; ++c) { ee[c] = __expf(pmL[c] - mm2); ls = fmaf(ee[c], plL[c], ls); }
    float inv = 1.f / ls;
    float sv = 0.f;
#pragma unroll
    for (int c = 0; c < 8; ++c) {
      float pv = (c == tch) ? ab : gld(&pacc[(size_t)(b*8+c)*HH + tid]);
      sv = fmaf(ee[c], pv, sv);
    }
    const float sxv = sv * inv;            // sx stays in a register
    if (tid < 50) {
      float a = __expf(stL[tid] - mm2) * inv;
      gst(ax_rot + (size_t)par*BB*AXP + (size_t)b*AXP + t0 + tid, a);
      p.out[AOFF + (size_t)b*NSTEP*TT + (size_t)s*TT + t0 + tid] = a;
    }
    if (s < NSTEP-1) ixh[tid] = (_Float16)(embr + sxv);
    __syncthreads();
    // ---- GRU first (publishes hx + flag ASAP) ----
    if (s < NSTEP-1) gru_step(s);
    // ---- FC (off critical path): Bh reuses ixh ----
    ixh[tid] = (_Float16)(hxL[tid] + sxv);
    __syncthreads();
    {
      const int rowg = hb + lane;
      const v2h* bp = (const v2h*)ixh;
      float pf = 0.f;
#pragma unroll 2
      for (int kb = 0; kb < 8; ++kb) {
        const int kbg = wave*8 + kb;
        const int pb  = kbg*4;
        v8h w = fwT[kbg*512 + rowg];
        DOT8(pf, w, bp[pb], bp[pb+1], bp[pb+2], bp[pb+3]);
      }
      redu[wave*64 + lane] = pf;
      __syncthreads();
      if (tid < 64) {
        float v = 0.f;
#pragma unroll
        for (int w = 0; w < 8; ++w) v += redu[w*64 + tid];
        const int r2 = hb + tid;
        if (r2 < VO)
          p.out[(size_t)b*NSTEP*VO + (size_t)s*VO + r2] = v + p.fb[r2];
      }
    }
  }
}

extern "C" void kernel_launch(void* const* d_in, const int* in_sizes, int n_in,
                              void* d_out, int out_size, void* d_ws, size_t ws_size,
                              hipStream_t stream) {
  P p;
  p.x   = (const float*)d_in[0];
  p.y   = (const int*)  d_in[1];
  p.emb = (const float*)d_in[2];
  p.wih = (const float*)d_in[3];
  p.whh = (const float*)d_in[4];
  p.bih = (const float*)d_in[5];
  p.bhh = (const float*)d_in[6];
  p.cw  = (const float*)d_in[7];
  p.cb  = (const float*)d_in[8];
  p.aw  = (const float*)d_in[9];
  p.ab  = (const float*)d_in[10];
  p.fw  = (const float*)d_in[11];
  p.fb  = (const float*)d_in[12];
  p.out = (float*)d_out;
  p.ctrl = (int*)d_ws;
  // layout: 48KB flags | fws floats (763,904B) | transposed fp16 weights (3.67MB)
  size_t flcount = (size_t)2*BB*HH + (size_t)2*BB*AXP + 512 + (size_t)BB*8*HH;
  p.fws = (float*)((char*)d_ws + 49152);
  p.w16 = (_Float16*)((char*)d_ws + 49152 + 4*flcount);

  hipMemsetAsync(d_ws, 0, 49152, stream);

  void* args[] = { &p };
  hipError_t err = hipLaunchCooperativeKernel((const void*)seq2seq_kernel,
                                              dim3(NBLK), dim3(NTHR), args, 0, stream);
  if (err != hipSuccess) {
    seq2seq_kernel<<<dim3(NBLK), dim3(NTHR), 0, stream>>>(p);
  }
}